// Round 4
// baseline (1547.864 us; speedup 1.0000x reference)
//
#include <hip/hip_runtime.h>
#include <hip/hip_bf16.h>

// Problem constants: B=4, LK=512, LQ=128, D=256, H=256, L=3
// d_in order: 0 keys[4,512,256] 1 queries[4,128,256] 2 W_k[256,256] 3 W_q[256,256]
//             4 w_v[1,256] 5 W_g_w[256,256] 6 W_g_b[256] 7 gru_Wih[3,768,256]
//             8 gru_Whh[3,768,256] 9 gru_bih[3,768] 10 gru_bhh[3,768]
// out: x [4,128,256] as float32

typedef __attribute__((ext_vector_type(8))) short short8;
typedef __attribute__((ext_vector_type(4))) float f32x4;

__device__ __forceinline__ float fast_rcp(float x) { return __builtin_amdgcn_rcpf(x); }
__device__ __forceinline__ float fast_tanh(float x) {
    float e = __expf(2.f * x);
    return 1.f - 2.f * fast_rcp(1.f + e);
}
__device__ __forceinline__ float fast_sigmoid(float x) {
    return fast_rcp(1.f + __expf(-x));
}
__device__ __forceinline__ unsigned short f2bf(float v) {
    unsigned int b = __builtin_bit_cast(unsigned int, v);
    unsigned int r = (b + 0x7fffu + ((b >> 16) & 1u)) >> 16;
    return (unsigned short)r;
}

// out[row, n] = sum_k in[row, k] * W[n, k] (+ bias[n]); K fixed at 256.
__global__ void gemm_rowwise(const float* __restrict__ in, const float* __restrict__ W,
                             const float* __restrict__ bias, float* __restrict__ out, int N) {
    __shared__ float xrow[256];
    const int tid = threadIdx.x;
    const int row = blockIdx.x;
    xrow[tid] = in[row * 256 + tid];
    __syncthreads();
    const float4* xv = (const float4*)xrow;
    for (int n = tid; n < N; n += 256) {
        const float4* wv = (const float4*)(W + n * 256);
        float s = 0.f;
#pragma unroll 8
        for (int k4 = 0; k4 < 64; ++k4) {
            float4 a = xv[k4];
            float4 b = wv[k4];
            s += a.x * b.x + a.y * b.y + a.z * b.z + a.w * b.w;
        }
        if (bias) s += bias[n];
        out[row * N + n] = s;
    }
}

// e[b,q,k] = exp( sum_h w_v[h]*tanh(Qp[b,q,h]+Kp[b,k,h]) ); denom[q] += sum over (b,k)
__global__ void attn_scores(const float* __restrict__ Kp, const float* __restrict__ Qp,
                            const float* __restrict__ wv, float* __restrict__ e,
                            float* __restrict__ denom) {
    __shared__ float qrow[256];
    __shared__ float wvr[256];
    __shared__ float wsum[4];
    const int tid = threadIdx.x;
    const int row = blockIdx.x;      // b*128 + q
    const int b = row >> 7, q = row & 127;
    qrow[tid] = Qp[row * 256 + tid];
    wvr[tid] = wv[tid];
    __syncthreads();
    const int lane = tid & 63, w = tid >> 6;
    const float4 qv = ((const float4*)qrow)[lane];
    const float4 wvv = ((const float4*)wvr)[lane];
    float dsum = 0.f;
    for (int k = w; k < 512; k += 4) {
        const float4 kv = *(const float4*)(Kp + (b * 512 + k) * 256 + lane * 4);
        float s = fast_tanh(qv.x + kv.x) * wvv.x;
        s += fast_tanh(qv.y + kv.y) * wvv.y;
        s += fast_tanh(qv.z + kv.z) * wvv.z;
        s += fast_tanh(qv.w + kv.w) * wvv.w;
#pragma unroll
        for (int m = 1; m < 64; m <<= 1) s += __shfl_xor(s, m);
        if (lane == 0) {
            float ev = __expf(s);
            e[row * 512 + k] = ev;
            dsum += ev;
        }
    }
    if (lane == 0) wsum[w] = dsum;
    __syncthreads();
    if (tid == 0) atomicAdd(&denom[q], wsum[0] + wsum[1] + wsum[2] + wsum[3]);
}

// rep + gate + x0
__global__ void rep_gate(const float* __restrict__ e, const float* __restrict__ denom,
                         const float* __restrict__ keys, const float* __restrict__ queries,
                         const float* __restrict__ Wg, const float* __restrict__ bg,
                         float* __restrict__ x0) {
    __shared__ float att[512];
    __shared__ float urow[256];
    const int tid = threadIdx.x;
    const int row = blockIdx.x;      // b*128 + q
    const int b = row >> 7, q = row & 127;
    const float inv = 1.f / denom[q];
    att[tid] = e[row * 512 + tid] * inv;
    att[tid + 256] = e[row * 512 + 256 + tid] * inv;
    __syncthreads();
    float racc = 0.f;
#pragma unroll 4
    for (int k = 0; k < 512; ++k) racc += att[k] * keys[(b * 512 + k) * 256 + tid];
    const float u = queries[row * 256 + tid] + racc;
    urow[tid] = u;
    __syncthreads();
    const float4* uv = (const float4*)urow;
    const float4* wr = (const float4*)(Wg + tid * 256);
    float g = 0.f;
#pragma unroll 8
    for (int k4 = 0; k4 < 64; ++k4) {
        float4 a = uv[k4];
        float4 wq = wr[k4];
        g += a.x * wq.x + a.y * wq.y + a.z * wq.z + a.w * wq.w;
    }
    g += bg[tid];
    x0[row * 256 + tid] = fast_sigmoid(g) * u;
}

// Sequential GRU layer: 1 workgroup, 8 waves. Whh (f32->bf16 in-register) resident
// in VGPRs as MFMA B-fragments (192 VGPR/wave). Per step: gh = h@Whh^T via
// 48 MFMA(16x16x32)/wave (M=4 padded to 16). Single barrier/step via abuf dbuf.
// launch_bounds(512,1): round-3 evidence showed (512,2) capped VGPRs at 128 and
// spilled bf[] to scratch (380us, L2-bound). 1 keeps the cap at >=256.
__launch_bounds__(512, 1)
__global__ void gru_seq(const float* __restrict__ gi,          // [512][768] (includes bih)
                        const float* __restrict__ whh,          // [768][256] f32 row-major
                        const float* __restrict__ bhh,          // [768]
                        float* __restrict__ xout) {             // [512][256]
    // abuf[buf][ks][hi][row][j]: bf16 A-fragment; element (row=batch, k=ks*32+hi*8+j)
    __shared__ __align__(16) unsigned short abuf[2][8][4][16][8];  // 16KB
    __shared__ float gibuf[2][3072];                               // 24KB (gi row dbuf)

    const int tid = threadIdx.x;
    const int lane = tid & 63, w = tid >> 6;
    const int l15 = lane & 15, lhi = lane >> 4;

    // zero both abuf buffers (rows 4..15 stay zero forever -> padded M)
    for (int i = tid; i < 8192; i += 512) ((unsigned short*)abuf)[i] = 0;

    // B-fragment preload (f32 -> bf16): wave w owns tiles {2w,2w+1, 16+2w,16+2w+1, 32+2w,32+2w+1}
    short8 bf[6][8];
    {
        const int t0 = 2 * w, t1 = 2 * w + 1;
        const int tiles[6] = {t0, t1, 16 + t0, 16 + t1, 32 + t0, 32 + t1};
#pragma unroll
        for (int i = 0; i < 6; ++i) {
            const float* basef = whh + (tiles[i] * 16 + l15) * 256 + lhi * 8;
#pragma unroll
            for (int ks = 0; ks < 8; ++ks) {
                const float4 a0 = *(const float4*)(basef + ks * 32);
                const float4 a1 = *(const float4*)(basef + ks * 32 + 4);
                short8 v;
                v[0] = (short)f2bf(a0.x); v[1] = (short)f2bf(a0.y);
                v[2] = (short)f2bf(a0.z); v[3] = (short)f2bf(a0.w);
                v[4] = (short)f2bf(a1.x); v[5] = (short)f2bf(a1.y);
                v[6] = (short)f2bf(a1.z); v[7] = (short)f2bf(a1.w);
                bf[i][ks] = v;
            }
        }
    }
    // bias preload (valid for lanes 0-15)
    float bh0[2], bh1[2], bh2[2];
#pragma unroll
    for (int p = 0; p < 2; ++p) {
        const int hc = 32 * w + 16 * p + l15;
        bh0[p] = bhh[hc];
        bh1[p] = bhh[256 + hc];
        bh2[p] = bhh[512 + hc];
    }
    // h state in registers: lane (l15<16) owns (hc=32w+16p+l15, b) for p in {0,1}, b in {0..3}
    float hreg[2][4];
#pragma unroll
    for (int p = 0; p < 2; ++p)
#pragma unroll
        for (int b = 0; b < 4; ++b) hreg[p][b] = 0.f;

    // preload gi row 0 into gibuf[0]
#pragma unroll
    for (int m = 0; m < 6; ++m) {
        const int j = tid + 512 * m;
        const int b = j / 768, c = j - b * 768;
        gibuf[0][j] = gi[b * 98304 + c];
    }
    __syncthreads();

    for (int t = 0; t < 128; ++t) {
        // async prefetch gi row t+1 -> gibuf[(t+1)&1] (global_load_lds, width 4).
        // 64-lane chunks never cross a batch boundary (768 % 64 == 0), so the
        // wave-uniform LDS base + lane*4 contract holds.
        if (t < 127) {
#pragma unroll
            for (int m = 0; m < 6; ++m) {
                const int jw = (w << 6) + 512 * m;       // wave-uniform chunk base
                const int jl = jw + lane;                // per-lane element
                const int b = jl / 768, c = jl - b * 768;
                const float* gsrc = gi + b * 98304 + (t + 1) * 768 + c;
                __builtin_amdgcn_global_load_lds(
                    (const __attribute__((address_space(1))) unsigned int*)gsrc,
                    (__attribute__((address_space(3))) unsigned int*)&gibuf[(t + 1) & 1][jw],
                    4, 0, 0);
            }
        }
        // MFMA: gh = h~ @ Whh^T (reads abuf[t&1])
        f32x4 acc[6];
#pragma unroll
        for (int i = 0; i < 6; ++i)
#pragma unroll
            for (int c = 0; c < 4; ++c) acc[i][c] = 0.f;
#pragma unroll
        for (int ks = 0; ks < 8; ++ks) {
            const short8 a = *(const short8*)&abuf[t & 1][ks][lhi][l15][0];
#pragma unroll
            for (int i = 0; i < 6; ++i)
                acc[i] = __builtin_amdgcn_mfma_f32_16x16x32_bf16(a, bf[i][ks], acc[i], 0, 0, 0);
        }

        // epilogue: lanes 0-15 own (batch=c-reg, col=l15) of each output tile
        if (lane < 16) {
            const float* gcur = gibuf[t & 1];
#pragma unroll
            for (int p = 0; p < 2; ++p) {
                const int hc = 32 * w + 16 * p + l15;
#pragma unroll
                for (int b = 0; b < 4; ++b) {
                    const float ghr = acc[0 + p][b] + bh0[p];
                    const float ghz = acc[2 + p][b] + bh1[p];
                    const float ghn = acc[4 + p][b] + bh2[p];
                    const float gir = gcur[b * 768 + hc];
                    const float giz = gcur[b * 768 + 256 + hc];
                    const float gin = gcur[b * 768 + 512 + hc];
                    const float r = fast_sigmoid(gir + ghr);
                    const float z = fast_sigmoid(giz + ghz);
                    const float nn = fast_tanh(gin + r * ghn);
                    const float hn = nn + z * (hreg[p][b] - nn);
                    hreg[p][b] = hn;
                    xout[(b * 128 + t) * 256 + hc] = hn;
                    abuf[(t + 1) & 1][hc >> 5][(hc >> 3) & 3][b][hc & 7] = f2bf(hn);
                }
            }
        }
        // one barrier/step: publishes abuf[(t+1)&1] + gibuf[(t+1)&1] (syncthreads
        // drains vmcnt -> global_load_lds data visible) for step t+1.
        __syncthreads();
    }
}

extern "C" void kernel_launch(void* const* d_in, const int* in_sizes, int n_in,
                              void* d_out, int out_size, void* d_ws, size_t ws_size,
                              hipStream_t stream) {
    (void)in_sizes; (void)n_in; (void)out_size; (void)ws_size;
    const float* keys    = (const float*)d_in[0];
    const float* queries = (const float*)d_in[1];
    const float* W_k     = (const float*)d_in[2];
    const float* W_q     = (const float*)d_in[3];
    const float* w_v     = (const float*)d_in[4];
    const float* W_g_w   = (const float*)d_in[5];
    const float* W_g_b   = (const float*)d_in[6];
    const float* Wih     = (const float*)d_in[7];
    const float* Whh     = (const float*)d_in[8];
    const float* bih     = (const float*)d_in[9];
    const float* bhh     = (const float*)d_in[10];

    float* ws = (float*)d_ws;
    float* Kp_gi = ws;             // 524288 (Kp; reused as gi after attention phase)
    float* Qp   = ws + 524288;     // 131072
    float* e    = ws + 655360;     // 262144
    float* den  = ws + 917504;     // 256 (128 used)
    float* xA   = ws + 917760;     // 131072
    float* xB   = ws + 1048832;    // 131072

    hipMemsetAsync((void*)den, 0, 512, stream);

    gemm_rowwise<<<2048, 256, 0, stream>>>(keys, W_k, nullptr, Kp_gi, 256);
    gemm_rowwise<<<512, 256, 0, stream>>>(queries, W_q, nullptr, Qp, 256);
    attn_scores<<<512, 256, 0, stream>>>(Kp_gi, Qp, w_v, e, den);
    rep_gate<<<512, 256, 0, stream>>>(e, den, keys, queries, W_g_w, W_g_b, xA);

    float* gi = Kp_gi;   // Kp dead after attn_scores
    float* x1 = xB;
    float* x2 = xA;      // reuse xA for layer-1 output
    gemm_rowwise<<<512, 256, 0, stream>>>(xA, Wih, bih, gi, 768);
    gru_seq<<<1, 512, 0, stream>>>(gi, Whh, bhh, x1);
    gemm_rowwise<<<512, 256, 0, stream>>>(x1, Wih + 196608, bih + 768, gi, 768);
    gru_seq<<<1, 512, 0, stream>>>(gi, Whh + 196608, bhh + 768, x2);
    gemm_rowwise<<<512, 256, 0, stream>>>(x2, Wih + 393216, bih + 1536, gi, 768);
    gru_seq<<<1, 512, 0, stream>>>(gi, Whh + 393216, bhh + 1536, (float*)d_out);
}

// Round 5
// 1342.835 us; speedup vs baseline: 1.1527x; 1.1527x over previous
//
#include <hip/hip_runtime.h>
#include <hip/hip_bf16.h>

// Problem constants: B=4, LK=512, LQ=128, D=256, H=256, L=3
// out: x [4,128,256] float32

typedef __attribute__((ext_vector_type(8))) short short8;
typedef __attribute__((ext_vector_type(4))) short short4_t;
typedef __attribute__((ext_vector_type(4))) float f32x4;
typedef unsigned short ushort;

__device__ __forceinline__ float fast_rcp(float x) { return __builtin_amdgcn_rcpf(x); }
__device__ __forceinline__ float fast_tanh(float x) {
    float e = __expf(2.f * x);
    return 1.f - 2.f * fast_rcp(1.f + e);
}
__device__ __forceinline__ float fast_sigmoid(float x) {
    return fast_rcp(1.f + __expf(-x));
}
__device__ __forceinline__ ushort f2bf(float v) {
    unsigned int b = __builtin_bit_cast(unsigned int, v);
    unsigned int r = (b + 0x7fffu + ((b >> 16) & 1u)) >> 16;
    return (ushort)r;
}

// out[row, n] = sum_k in[row, k] * W[n, k] (+ bias[n]) (+ bias2[n] for n<512); K=256.
__global__ void gemm_rowwise(const float* __restrict__ in, const float* __restrict__ W,
                             const float* __restrict__ bias, const float* __restrict__ bias2,
                             float* __restrict__ out, int N) {
    __shared__ float xrow[256];
    const int tid = threadIdx.x;
    const int row = blockIdx.x;
    xrow[tid] = in[row * 256 + tid];
    __syncthreads();
    const float4* xv = (const float4*)xrow;
    for (int n = tid; n < N; n += 256) {
        const float4* wv = (const float4*)(W + n * 256);
        float s = 0.f;
#pragma unroll 8
        for (int k4 = 0; k4 < 64; ++k4) {
            float4 a = xv[k4];
            float4 b = wv[k4];
            s += a.x * b.x + a.y * b.y + a.z * b.z + a.w * b.w;
        }
        if (bias) s += bias[n];
        if (bias2 && n < 512) s += bias2[n];
        out[row * N + n] = s;
    }
}

// e[b,q,k] = exp( sum_h w_v[h]*tanh(Qp[b,q,h]+Kp[b,k,h]) ); denom[q] += sum over (b,k)
__global__ void attn_scores(const float* __restrict__ Kp, const float* __restrict__ Qp,
                            const float* __restrict__ wv, float* __restrict__ e,
                            float* __restrict__ denom) {
    __shared__ float qrow[256];
    __shared__ float wvr[256];
    __shared__ float wsum[4];
    const int tid = threadIdx.x;
    const int row = blockIdx.x;      // b*128 + q
    const int b = row >> 7, q = row & 127;
    qrow[tid] = Qp[row * 256 + tid];
    wvr[tid] = wv[tid];
    __syncthreads();
    const int lane = tid & 63, w = tid >> 6;
    const float4 qv = ((const float4*)qrow)[lane];
    const float4 wvv = ((const float4*)wvr)[lane];
    float dsum = 0.f;
    for (int k = w; k < 512; k += 4) {
        const float4 kv = *(const float4*)(Kp + (b * 512 + k) * 256 + lane * 4);
        float s = fast_tanh(qv.x + kv.x) * wvv.x;
        s += fast_tanh(qv.y + kv.y) * wvv.y;
        s += fast_tanh(qv.z + kv.z) * wvv.z;
        s += fast_tanh(qv.w + kv.w) * wvv.w;
#pragma unroll
        for (int m = 1; m < 64; m <<= 1) s += __shfl_xor(s, m);
        if (lane == 0) {
            float ev = __expf(s);
            e[row * 512 + k] = ev;
            dsum += ev;
        }
    }
    if (lane == 0) wsum[w] = dsum;
    __syncthreads();
    if (tid == 0) atomicAdd(&denom[q], wsum[0] + wsum[1] + wsum[2] + wsum[3]);
}

// rep + gate + x0
__global__ void rep_gate(const float* __restrict__ e, const float* __restrict__ denom,
                         const float* __restrict__ keys, const float* __restrict__ queries,
                         const float* __restrict__ Wg, const float* __restrict__ bg,
                         float* __restrict__ x0) {
    __shared__ float att[512];
    __shared__ float urow[256];
    const int tid = threadIdx.x;
    const int row = blockIdx.x;      // b*128 + q
    const int b = row >> 7, q = row & 127;
    const float inv = 1.f / denom[q];
    att[tid] = e[row * 512 + tid] * inv;
    att[tid + 256] = e[row * 512 + 256 + tid] * inv;
    __syncthreads();
    float racc = 0.f;
#pragma unroll 4
    for (int k = 0; k < 512; ++k) racc += att[k] * keys[(b * 512 + k) * 256 + tid];
    const float u = queries[row * 256 + tid] + racc;
    urow[tid] = u;
    __syncthreads();
    const float4* uv = (const float4*)urow;
    const float4* wr = (const float4*)(Wg + tid * 256);
    float g = 0.f;
#pragma unroll 8
    for (int k4 = 0; k4 < 64; ++k4) {
        float4 a = uv[k4];
        float4 wq = wr[k4];
        g += a.x * wq.x + a.y * wq.y + a.z * wq.z + a.w * wq.w;
    }
    g += bg[tid];
    x0[row * 256 + tid] = fast_sigmoid(g) * u;
}

// Sequential GRU layer: 1 workgroup, 4 waves (256 thr) -> 1 wave/SIMD -> 512-reg
// budget/wave (r3/r4 evidence: 8-wave blocks cap at 256 combined VGPR+AGPR and
// spill the 192-reg weight array; 380-430us L2-bound). Wave w owns output cols
// [64w,64w+64) of all 3 gates: bf[12][8] = 384 regs resident.
// Per step: phase A = 96 MFMA/wave + acc->gbuf; phase B = all 256 threads do
// gate math (4 h each) + write abuf (XOR row-swizzle vs 16-way bank conflict).
__launch_bounds__(256, 1)
__global__ void gru_seq(const float* __restrict__ gi,    // [4][128][768] (biases folded: r,z += bhh)
                        const float* __restrict__ whh,   // [768][256] f32 row-major
                        const float* __restrict__ bhh,   // [768] (only n-part used here)
                        float* __restrict__ xout) {      // [4][128][256]
    // abuf[buf][grp=ks*4+khi][physrow][j]: bf16 A-fragments, physrow = logicalrow ^ (grp&15)
    __shared__ __align__(16) ushort abuf[2][32][16][8];   // 16KB
    __shared__ float gibuf[2][3072];                      // 24KB (gi row dbuf)
    __shared__ float gbuf[3][4][256];                     // 12KB (gate values gh)

    const int tid = threadIdx.x;
    const int lane = tid & 63, w = tid >> 6;
    const int l15 = lane & 15, lhi = lane >> 4;

    // zero both abuf buffers (logical rows 4..15 must read as zero -> padded M)
    for (int i = tid; i < 8192; i += 256) ((ushort*)abuf)[i] = 0;

    // B-fragment preload (f32 -> bf16): wave w, tile i = g*4+c covers Whh rows
    // g*256 + 64w + 16c + l15, k = ks*32 + lhi*8 + j
    short8 bf[12][8];
#pragma unroll
    for (int g = 0; g < 3; ++g)
#pragma unroll
        for (int c = 0; c < 4; ++c) {
            const float* basef = whh + (g * 256 + w * 64 + c * 16 + l15) * 256 + lhi * 8;
#pragma unroll
            for (int ks = 0; ks < 8; ++ks) {
                const float4 a0 = *(const float4*)(basef + ks * 32);
                const float4 a1 = *(const float4*)(basef + ks * 32 + 4);
                short8 v;
                v[0] = (short)f2bf(a0.x); v[1] = (short)f2bf(a0.y);
                v[2] = (short)f2bf(a0.z); v[3] = (short)f2bf(a0.w);
                v[4] = (short)f2bf(a1.x); v[5] = (short)f2bf(a1.y);
                v[6] = (short)f2bf(a1.z); v[7] = (short)f2bf(a1.w);
                bf[g * 4 + c][ks] = v;
            }
        }

    // phase-B constants: thread owns (batch pb_b, h-cols pb_h..pb_h+3)
    const int pb_b = tid >> 6;
    const int pb_h = (tid & 63) << 2;
    const f32x4 bn4 = *(const f32x4*)(bhh + 512 + pb_h);  // n-gate hidden bias
    float hreg[4] = {0.f, 0.f, 0.f, 0.f};

    // preload gi row 0 into gibuf[0]
#pragma unroll
    for (int m = 0; m < 12; ++m) {
        const int j = tid + 256 * m;
        const int b = j / 768, c = j - b * 768;
        gibuf[0][j] = gi[b * 98304 + c];
    }
    __syncthreads();

    for (int t = 0; t < 128; ++t) {
        // async prefetch gi row t+1 -> gibuf[(t+1)&1]. Chunks of 64 lanes never
        // cross a batch boundary (768 % 64 == 0): wave-uniform LDS base + lane*4.
        if (t < 127) {
#pragma unroll
            for (int m = 0; m < 12; ++m) {
                const int jw = m * 256 + (w << 6);
                const int jl = jw + lane;
                const int b = jl / 768, c = jl - b * 768;
                const float* gsrc = gi + b * 98304 + (t + 1) * 768 + c;
                __builtin_amdgcn_global_load_lds(
                    (const __attribute__((address_space(1))) unsigned int*)gsrc,
                    (__attribute__((address_space(3))) unsigned int*)&gibuf[(t + 1) & 1][jw],
                    4, 0, 0);
            }
        }
        // phase A: gh = h~ @ Whh^T (reads abuf[t&1], XOR-swizzled rows)
        f32x4 acc[12];
#pragma unroll
        for (int i = 0; i < 12; ++i)
#pragma unroll
            for (int cc = 0; cc < 4; ++cc) acc[i][cc] = 0.f;
#pragma unroll
        for (int ks = 0; ks < 8; ++ks) {
            const int grp = ks * 4 + lhi;
            const short8 a = *(const short8*)&abuf[t & 1][grp][l15 ^ (grp & 15)][0];
#pragma unroll
            for (int i = 0; i < 12; ++i)
                acc[i] = __builtin_amdgcn_mfma_f32_16x16x32_bf16(a, bf[i][ks], acc[i], 0, 0, 0);
        }
        // acc -> gbuf: lanes 0-15 hold real rows (b = reg idx), col = l15
        if (lane < 16) {
#pragma unroll
            for (int g = 0; g < 3; ++g)
#pragma unroll
                for (int c = 0; c < 4; ++c)
#pragma unroll
                    for (int b = 0; b < 4; ++b)
                        gbuf[g][b][(w << 6) + (c << 4) + l15] = acc[g * 4 + c][b];
        }
        __syncthreads();

        // phase B: all 256 threads, 4 h each
        {
            const float* gcur = gibuf[t & 1];
            const f32x4 gr = *(const f32x4*)&gbuf[0][pb_b][pb_h];
            const f32x4 gz = *(const f32x4*)&gbuf[1][pb_b][pb_h];
            const f32x4 gn = *(const f32x4*)&gbuf[2][pb_b][pb_h];
            const f32x4 ir = *(const f32x4*)&gcur[pb_b * 768 + pb_h];
            const f32x4 iz = *(const f32x4*)&gcur[pb_b * 768 + 256 + pb_h];
            const f32x4 in_ = *(const f32x4*)&gcur[pb_b * 768 + 512 + pb_h];
            f32x4 xo;
            short4_t hb;
#pragma unroll
            for (int j = 0; j < 4; ++j) {
                const float r = fast_sigmoid(ir[j] + gr[j]);          // biases pre-folded in gi
                const float z = fast_sigmoid(iz[j] + gz[j]);
                const float hn_pre = gn[j] + bn4[j];                  // bhh_n not foldable (r*)
                const float nn = fast_tanh(in_[j] + r * hn_pre);
                const float h2 = nn + z * (hreg[j] - nn);
                hreg[j] = h2;
                xo[j] = h2;
                hb[j] = (short)f2bf(h2);
            }
            *(f32x4*)&xout[(pb_b * 128 + t) * 256 + pb_h] = xo;
            // abuf write for step t+1: k-index = pb_h..pb_h+3
            const int grp = pb_h >> 3;                                 // ks*4+khi
            ushort* dst = &abuf[(t + 1) & 1][grp][pb_b ^ (grp & 15)][pb_h & 7];
            *(short4_t*)dst = hb;
        }
        __syncthreads();   // abuf[(t+1)], gbuf reuse, gibuf prefetch all published
    }
}

extern "C" void kernel_launch(void* const* d_in, const int* in_sizes, int n_in,
                              void* d_out, int out_size, void* d_ws, size_t ws_size,
                              hipStream_t stream) {
    (void)in_sizes; (void)n_in; (void)out_size; (void)ws_size;
    const float* keys    = (const float*)d_in[0];
    const float* queries = (const float*)d_in[1];
    const float* W_k     = (const float*)d_in[2];
    const float* W_q     = (const float*)d_in[3];
    const float* w_v     = (const float*)d_in[4];
    const float* W_g_w   = (const float*)d_in[5];
    const float* W_g_b   = (const float*)d_in[6];
    const float* Wih     = (const float*)d_in[7];
    const float* Whh     = (const float*)d_in[8];
    const float* bih     = (const float*)d_in[9];
    const float* bhh     = (const float*)d_in[10];

    float* ws = (float*)d_ws;
    float* Kp_gi = ws;             // 524288 (Kp; reused as gi after attention phase)
    float* Qp   = ws + 524288;     // 131072
    float* e    = ws + 655360;     // 262144
    float* den  = ws + 917504;     // 256 (128 used)
    float* xA   = ws + 917760;     // 131072
    float* xB   = ws + 1048832;    // 131072

    hipMemsetAsync((void*)den, 0, 512, stream);

    gemm_rowwise<<<2048, 256, 0, stream>>>(keys, W_k, nullptr, nullptr, Kp_gi, 256);
    gemm_rowwise<<<512, 256, 0, stream>>>(queries, W_q, nullptr, nullptr, Qp, 256);
    attn_scores<<<512, 256, 0, stream>>>(Kp_gi, Qp, w_v, e, den);
    rep_gate<<<512, 256, 0, stream>>>(e, den, keys, queries, W_g_w, W_g_b, xA);

    float* gi = Kp_gi;   // Kp dead after attn_scores
    // gi GEMM bias: bih fully, plus bhh folded into r,z halves (n<512)
    gemm_rowwise<<<512, 256, 0, stream>>>(xA, Wih, bih, bhh, gi, 768);
    gru_seq<<<1, 256, 0, stream>>>(gi, Whh, bhh, xB);
    gemm_rowwise<<<512, 256, 0, stream>>>(xB, Wih + 196608, bih + 768, bhh + 768, gi, 768);
    gru_seq<<<1, 256, 0, stream>>>(gi, Whh + 196608, bhh + 768, xA);
    gemm_rowwise<<<512, 256, 0, stream>>>(xA, Wih + 393216, bih + 1536, bhh + 1536, gi, 768);
    gru_seq<<<1, 256, 0, stream>>>(gi, Whh + 393216, bhh + 1536, (float*)d_out);
}

// Round 6
// 1107.457 us; speedup vs baseline: 1.3977x; 1.2125x over previous
//
#include <hip/hip_runtime.h>
#include <hip/hip_bf16.h>

// Problem constants: B=4, LK=512, LQ=128, D=256, H=256, L=3
// out: x [4,128,256] float32

typedef __attribute__((ext_vector_type(8))) short short8;
typedef __attribute__((ext_vector_type(4))) short short4_t;
typedef __attribute__((ext_vector_type(4))) float f32x4;
typedef __attribute__((ext_vector_type(4))) int i32x4;
typedef unsigned short ushort;

__device__ __forceinline__ float fast_rcp(float x) { return __builtin_amdgcn_rcpf(x); }
__device__ __forceinline__ float fast_tanh(float x) {
    float e = __expf(2.f * x);
    return 1.f - 2.f * fast_rcp(1.f + e);
}
__device__ __forceinline__ float fast_sigmoid(float x) {
    return fast_rcp(1.f + __expf(-x));
}
__device__ __forceinline__ ushort f2bf(float v) {
    unsigned int b = __builtin_bit_cast(unsigned int, v);
    unsigned int r = (b + 0x7fffu + ((b >> 16) & 1u)) >> 16;
    return (ushort)r;
}

// out[row, n] = sum_k in[row, k] * W[n, k] (+ bias[n]) (+ bias2[n] for n<512); K=256.
__global__ void gemm_rowwise(const float* __restrict__ in, const float* __restrict__ W,
                             const float* __restrict__ bias, const float* __restrict__ bias2,
                             float* __restrict__ out, int N) {
    __shared__ float xrow[256];
    const int tid = threadIdx.x;
    const int row = blockIdx.x;
    xrow[tid] = in[row * 256 + tid];
    __syncthreads();
    const float4* xv = (const float4*)xrow;
    for (int n = tid; n < N; n += 256) {
        const float4* wv = (const float4*)(W + n * 256);
        float s = 0.f;
#pragma unroll 8
        for (int k4 = 0; k4 < 64; ++k4) {
            float4 a = xv[k4];
            float4 b = wv[k4];
            s += a.x * b.x + a.y * b.y + a.z * b.z + a.w * b.w;
        }
        if (bias) s += bias[n];
        if (bias2 && n < 512) s += bias2[n];
        out[row * N + n] = s;
    }
}

// e[b,q,k] = exp( sum_h w_v[h]*tanh(Qp[b,q,h]+Kp[b,k,h]) ); denom[q] += sum over (b,k)
__global__ void attn_scores(const float* __restrict__ Kp, const float* __restrict__ Qp,
                            const float* __restrict__ wv, float* __restrict__ e,
                            float* __restrict__ denom) {
    __shared__ float qrow[256];
    __shared__ float wvr[256];
    __shared__ float wsum[4];
    const int tid = threadIdx.x;
    const int row = blockIdx.x;      // b*128 + q
    const int b = row >> 7, q = row & 127;
    qrow[tid] = Qp[row * 256 + tid];
    wvr[tid] = wv[tid];
    __syncthreads();
    const int lane = tid & 63, w = tid >> 6;
    const float4 qv = ((const float4*)qrow)[lane];
    const float4 wvv = ((const float4*)wvr)[lane];
    float dsum = 0.f;
    for (int k = w; k < 512; k += 4) {
        const float4 kv = *(const float4*)(Kp + (b * 512 + k) * 256 + lane * 4);
        float s = fast_tanh(qv.x + kv.x) * wvv.x;
        s += fast_tanh(qv.y + kv.y) * wvv.y;
        s += fast_tanh(qv.z + kv.z) * wvv.z;
        s += fast_tanh(qv.w + kv.w) * wvv.w;
#pragma unroll
        for (int m = 1; m < 64; m <<= 1) s += __shfl_xor(s, m);
        if (lane == 0) {
            float ev = __expf(s);
            e[row * 512 + k] = ev;
            dsum += ev;
        }
    }
    if (lane == 0) wsum[w] = dsum;
    __syncthreads();
    if (tid == 0) atomicAdd(&denom[q], wsum[0] + wsum[1] + wsum[2] + wsum[3]);
}

// rep + gate + x0
__global__ void rep_gate(const float* __restrict__ e, const float* __restrict__ denom,
                         const float* __restrict__ keys, const float* __restrict__ queries,
                         const float* __restrict__ Wg, const float* __restrict__ bg,
                         float* __restrict__ x0) {
    __shared__ float att[512];
    __shared__ float urow[256];
    const int tid = threadIdx.x;
    const int row = blockIdx.x;      // b*128 + q
    const int b = row >> 7, q = row & 127;
    const float inv = 1.f / denom[q];
    att[tid] = e[row * 512 + tid] * inv;
    att[tid + 256] = e[row * 512 + 256 + tid] * inv;
    __syncthreads();
    float racc = 0.f;
#pragma unroll 4
    for (int k = 0; k < 512; ++k) racc += att[k] * keys[(b * 512 + k) * 256 + tid];
    const float u = queries[row * 256 + tid] + racc;
    urow[tid] = u;
    __syncthreads();
    const float4* uv = (const float4*)urow;
    const float4* wr = (const float4*)(Wg + tid * 256);
    float g = 0.f;
#pragma unroll 8
    for (int k4 = 0; k4 < 64; ++k4) {
        float4 a = uv[k4];
        float4 wq = wr[k4];
        g += a.x * wq.x + a.y * wq.y + a.z * wq.z + a.w * wq.w;
    }
    g += bg[tid];
    x0[row * 256 + tid] = fast_sigmoid(g) * u;
}

// Sequential GRU layer: 1 WG, 4 waves (1/SIMD, 512-reg unified budget/wave).
// Wave w owns output cols [64w,64w+64) of all 3 gates = 12 tiles.
// r5 evidence: builtin MFMA with AGPR-overflowed B operands makes LLVM emit
// v_accvgpr_read copies per use (~384 VALU/step -> 30% VALUBusy, 390us).
// Fix: 8 tiles' B-fragments pinned in AGPR via inline-asm MFMA ("a" constraint,
// 8x8x4 = exactly 256 AGPRs, read directly by v_mfma); 4 tiles stay VGPR via
// builtin (128 VGPR). Phase B is wave-local -> single barrier/step.
__launch_bounds__(256, 1)
__global__ void gru_seq(const float* __restrict__ gi,    // [4][128][768] (bih + bhh_rz folded)
                        const float* __restrict__ whh,   // [768][256] f32 row-major
                        const float* __restrict__ bhh,   // [768] (n-part used)
                        float* __restrict__ xout) {      // [4][128][256]
    // abuf[buf][grp=ks*4+khi][physrow][j]: bf16 A-frags, physrow = logicalrow ^ (grp&15)
    __shared__ __align__(16) ushort abuf[2][32][16][8];   // 16KB
    __shared__ float gibuf[2][3072];                      // 24KB (gi row dbuf)
    __shared__ float gbuf[3][4][256];                     // 12KB [gate][batch][col]

    const int tid = threadIdx.x;
    const int lane = tid & 63, w = tid >> 6;
    const int l15 = lane & 15, lhi = lane >> 4;

    // zero both abuf buffers (logical rows 4..15 must read as zero -> padded M)
    for (int i = tid; i < 8192; i += 256) ((ushort*)abuf)[i] = 0;

    // B-fragment preload (f32 -> bf16): tile i = g*4+c covers Whh rows
    // g*256 + 64w + 16c + l15, k = ks*32 + lhi*8 + j. Tiles 0-3 -> VGPR (builtin),
    // tiles 4-11 -> AGPR (inline asm).
    short8 bf_v[4][8];
    i32x4  bf_a[8][8];
#pragma unroll
    for (int i = 0; i < 12; ++i) {
        const int g = i >> 2, c = i & 3;
        const float* basef = whh + (g * 256 + w * 64 + c * 16 + l15) * 256 + lhi * 8;
#pragma unroll
        for (int ks = 0; ks < 8; ++ks) {
            const float4 a0 = *(const float4*)(basef + ks * 32);
            const float4 a1 = *(const float4*)(basef + ks * 32 + 4);
            short8 v;
            v[0] = (short)f2bf(a0.x); v[1] = (short)f2bf(a0.y);
            v[2] = (short)f2bf(a0.z); v[3] = (short)f2bf(a0.w);
            v[4] = (short)f2bf(a1.x); v[5] = (short)f2bf(a1.y);
            v[6] = (short)f2bf(a1.z); v[7] = (short)f2bf(a1.w);
            if (i < 4) bf_v[i][ks] = v;
            else       bf_a[i - 4][ks] = __builtin_bit_cast(i32x4, v);
        }
    }

    // phase-B mapping (wave-local): thread = (batch pb_b, cols pb_c..pb_c+3) within wave w's 64 cols
    const int pb_b = lhi;                    // 0..3
    const int pb_c = (w << 6) + (l15 << 2);  // wave-local col block
    const f32x4 bn4 = *(const f32x4*)(bhh + 512 + pb_c);  // n-gate hidden bias
    float hreg[4] = {0.f, 0.f, 0.f, 0.f};

    // preload gi row 0 into gibuf[0]
#pragma unroll
    for (int m = 0; m < 12; ++m) {
        const int j = tid + 256 * m;
        const int b = j / 768, c = j - b * 768;
        gibuf[0][j] = gi[b * 98304 + c];
    }
    __syncthreads();

    for (int t = 0; t < 128; ++t) {
        // async prefetch gi row t+1 -> gibuf[(t+1)&1]; 64-lane chunks never cross a
        // batch boundary (768 % 64 == 0): wave-uniform LDS base + lane*4 contract ok.
        if (t < 127) {
#pragma unroll
            for (int m = 0; m < 12; ++m) {
                const int jw = m * 256 + (w << 6);
                const int jl = jw + lane;
                const int b = jl / 768, c = jl - b * 768;
                const float* gsrc = gi + b * 98304 + (t + 1) * 768 + c;
                __builtin_amdgcn_global_load_lds(
                    (const __attribute__((address_space(1))) unsigned int*)gsrc,
                    (__attribute__((address_space(3))) unsigned int*)&gibuf[(t + 1) & 1][jw],
                    4, 0, 0);
            }
        }
        // phase A: gh = h~ @ Whh^T (reads abuf[t&1], XOR-swizzled rows)
        f32x4 acc[12];
#pragma unroll
        for (int i = 0; i < 12; ++i)
#pragma unroll
            for (int cc = 0; cc < 4; ++cc) acc[i][cc] = 0.f;
#pragma unroll
        for (int ks = 0; ks < 8; ++ks) {
            const int grp = ks * 4 + lhi;
            const short8 a = *(const short8*)&abuf[t & 1][grp][l15 ^ (grp & 15)][0];
#pragma unroll
            for (int i = 0; i < 4; ++i)
                acc[i] = __builtin_amdgcn_mfma_f32_16x16x32_bf16(a, bf_v[i][ks], acc[i], 0, 0, 0);
#pragma unroll
            for (int i = 0; i < 8; ++i)
                asm("v_mfma_f32_16x16x32_bf16 %0, %1, %2, %0"
                    : "+v"(acc[4 + i])
                    : "v"(a), "a"(bf_a[i][ks]));
        }
        // acc -> gbuf: lanes 0-15 hold real rows (b = reg idx), col = l15.
        // Wave-local: wave w writes only cols [64w,64w+64) which its own phase-B
        // threads read -> no barrier needed (compiler orders LDS w->r via lgkmcnt).
        if (lane < 16) {
#pragma unroll
            for (int g = 0; g < 3; ++g)
#pragma unroll
                for (int c = 0; c < 4; ++c)
#pragma unroll
                    for (int b = 0; b < 4; ++b)
                        gbuf[g][b][(w << 6) + (c << 4) + l15] = acc[g * 4 + c][b];
        }

        // phase B: all 64 lanes of wave w, 4 h each (batch pb_b, cols pb_c..pb_c+3)
        {
            const float* gcur = gibuf[t & 1];
            const f32x4 gr = *(const f32x4*)&gbuf[0][pb_b][pb_c];
            const f32x4 gz = *(const f32x4*)&gbuf[1][pb_b][pb_c];
            const f32x4 gn = *(const f32x4*)&gbuf[2][pb_b][pb_c];
            const f32x4 ir = *(const f32x4*)&gcur[pb_b * 768 + pb_c];
            const f32x4 iz = *(const f32x4*)&gcur[pb_b * 768 + 256 + pb_c];
            const f32x4 in_ = *(const f32x4*)&gcur[pb_b * 768 + 512 + pb_c];
            f32x4 xo;
            short4_t hb;
#pragma unroll
            for (int j = 0; j < 4; ++j) {
                const float r = fast_sigmoid(ir[j] + gr[j]);       // biases pre-folded in gi
                const float z = fast_sigmoid(iz[j] + gz[j]);
                const float hn_pre = gn[j] + bn4[j];               // bhh_n not foldable (r*)
                const float nn = fast_tanh(in_[j] + r * hn_pre);
                const float h2 = nn + z * (hreg[j] - nn);
                hreg[j] = h2;
                xo[j] = h2;
                hb[j] = (short)f2bf(h2);
            }
            *(f32x4*)&xout[(pb_b * 128 + t) * 256 + pb_c] = xo;
            // abuf write for step t+1: k-index = pb_c..pb_c+3 (pb_c&7 in {0,4} -> 8B aligned)
            const int grp = pb_c >> 3;
            ushort* dst = &abuf[(t + 1) & 1][grp][pb_b ^ (grp & 15)][pb_c & 7];
            *(short4_t*)dst = hb;
        }
        // single barrier/step: publishes abuf[(t+1)] cross-wave and gibuf[(t+1)]
        // (syncthreads drains vmcnt -> global_load_lds data visible).
        __syncthreads();
    }
}

extern "C" void kernel_launch(void* const* d_in, const int* in_sizes, int n_in,
                              void* d_out, int out_size, void* d_ws, size_t ws_size,
                              hipStream_t stream) {
    (void)in_sizes; (void)n_in; (void)out_size; (void)ws_size;
    const float* keys    = (const float*)d_in[0];
    const float* queries = (const float*)d_in[1];
    const float* W_k     = (const float*)d_in[2];
    const float* W_q     = (const float*)d_in[3];
    const float* w_v     = (const float*)d_in[4];
    const float* W_g_w   = (const float*)d_in[5];
    const float* W_g_b   = (const float*)d_in[6];
    const float* Wih     = (const float*)d_in[7];
    const float* Whh     = (const float*)d_in[8];
    const float* bih     = (const float*)d_in[9];
    const float* bhh     = (const float*)d_in[10];

    float* ws = (float*)d_ws;
    float* Kp_gi = ws;             // 524288 (Kp; reused as gi after attention phase)
    float* Qp   = ws + 524288;     // 131072
    float* e    = ws + 655360;     // 262144
    float* den  = ws + 917504;     // 256 (128 used)
    float* xA   = ws + 917760;     // 131072
    float* xB   = ws + 1048832;    // 131072

    hipMemsetAsync((void*)den, 0, 512, stream);

    gemm_rowwise<<<2048, 256, 0, stream>>>(keys, W_k, nullptr, nullptr, Kp_gi, 256);
    gemm_rowwise<<<512, 256, 0, stream>>>(queries, W_q, nullptr, nullptr, Qp, 256);
    attn_scores<<<512, 256, 0, stream>>>(Kp_gi, Qp, w_v, e, den);
    rep_gate<<<512, 256, 0, stream>>>(e, den, keys, queries, W_g_w, W_g_b, xA);

    float* gi = Kp_gi;   // Kp dead after attn_scores
    // gi GEMM bias: bih fully, plus bhh folded into r,z halves (n<512)
    gemm_rowwise<<<512, 256, 0, stream>>>(xA, Wih, bih, bhh, gi, 768);
    gru_seq<<<1, 256, 0, stream>>>(gi, Whh, bhh, xB);
    gemm_rowwise<<<512, 256, 0, stream>>>(xB, Wih + 196608, bih + 768, bhh + 768, gi, 768);
    gru_seq<<<1, 256, 0, stream>>>(gi, Whh + 196608, bhh + 768, xA);
    gemm_rowwise<<<512, 256, 0, stream>>>(xA, Wih + 393216, bih + 1536, bhh + 1536, gi, 768);
    gru_seq<<<1, 256, 0, stream>>>(gi, Whh + 393216, bhh + 1536, (float*)d_out);
}

// Round 10
// 1091.598 us; speedup vs baseline: 1.4180x; 1.0145x over previous
//
#include <hip/hip_runtime.h>
#include <hip/hip_bf16.h>

// Problem constants: B=4, LK=512, LQ=128, D=256, H=256, L=3
// out: x [4,128,256] float32

typedef __attribute__((ext_vector_type(8))) short short8;
typedef __attribute__((ext_vector_type(4))) short short4_t;
typedef __attribute__((ext_vector_type(4))) float f32x4;
typedef __attribute__((ext_vector_type(4))) int i32x4;
typedef unsigned short ushort;
typedef unsigned int uint;

__device__ __forceinline__ float fast_rcp(float x) { return __builtin_amdgcn_rcpf(x); }
__device__ __forceinline__ float fast_tanh(float x) {
    float e = __expf(2.f * x);
    return 1.f - 2.f * fast_rcp(1.f + e);
}
__device__ __forceinline__ float fast_sigmoid(float x) {
    return fast_rcp(1.f + __expf(-x));
}
__device__ __forceinline__ ushort f2bf(float v) {
    unsigned int b = __builtin_bit_cast(unsigned int, v);
    unsigned int r = (b + 0x7fffu + ((b >> 16) & 1u)) >> 16;
    return (ushort)r;
}

// 8-rows-per-block GEMM: out[row, n] = sum_k in[row, k] * W[n, k] (+ bias[n])
// (+ bias2[n] for n<512); K fixed at 256. W is read ONCE per 8 rows (r6 version
// re-read it per row: keys-proj alone was ~512MB L2 traffic).
__global__ void gemm_rowwise8(const float* __restrict__ in, const float* __restrict__ W,
                              const float* __restrict__ bias, const float* __restrict__ bias2,
                              float* __restrict__ out, int N) {
    __shared__ float xrow[8][256];
    const int tid = threadIdx.x;
    const int row0 = blockIdx.x * 8;
#pragma unroll
    for (int r = 0; r < 8; ++r) xrow[r][tid] = in[(row0 + r) * 256 + tid];
    __syncthreads();
    for (int n = tid; n < N; n += 256) {
        const float4* wv = (const float4*)(W + n * 256);
        float s[8] = {0.f, 0.f, 0.f, 0.f, 0.f, 0.f, 0.f, 0.f};
#pragma unroll 4
        for (int k4 = 0; k4 < 64; ++k4) {
            const float4 b = wv[k4];
#pragma unroll
            for (int r = 0; r < 8; ++r) {
                const float4 a = ((const float4*)xrow[r])[k4];   // broadcast read (free)
                s[r] += a.x * b.x + a.y * b.y + a.z * b.z + a.w * b.w;
            }
        }
        float bb = 0.f;
        if (bias) bb += bias[n];
        if (bias2 && n < 512) bb += bias2[n];
#pragma unroll
        for (int r = 0; r < 8; ++r) out[(row0 + r) * N + n] = s[r] + bb;
    }
}

// e[b,q,k] = exp( sum_h w_v[h]*tanh(Qp[b,q,h]+Kp[b,k,h]) ); denom[q] += sum over (b,k)
__global__ void attn_scores(const float* __restrict__ Kp, const float* __restrict__ Qp,
                            const float* __restrict__ wv, float* __restrict__ e,
                            float* __restrict__ denom) {
    __shared__ float qrow[256];
    __shared__ float wvr[256];
    __shared__ float wsum[4];
    const int tid = threadIdx.x;
    const int row = blockIdx.x;      // b*128 + q
    const int b = row >> 7, q = row & 127;
    qrow[tid] = Qp[row * 256 + tid];
    wvr[tid] = wv[tid];
    __syncthreads();
    const int lane = tid & 63, w = tid >> 6;
    const float4 qv = ((const float4*)qrow)[lane];
    const float4 wvv = ((const float4*)wvr)[lane];
    float dsum = 0.f;
    for (int k = w; k < 512; k += 4) {
        const float4 kv = *(const float4*)(Kp + (b * 512 + k) * 256 + lane * 4);
        float s = fast_tanh(qv.x + kv.x) * wvv.x;
        s += fast_tanh(qv.y + kv.y) * wvv.y;
        s += fast_tanh(qv.z + kv.z) * wvv.z;
        s += fast_tanh(qv.w + kv.w) * wvv.w;
#pragma unroll
        for (int m = 1; m < 64; m <<= 1) s += __shfl_xor(s, m);
        if (lane == 0) {
            float ev = __expf(s);
            e[row * 512 + k] = ev;
            dsum += ev;
        }
    }
    if (lane == 0) wsum[w] = dsum;
    __syncthreads();
    if (tid == 0) atomicAdd(&denom[q], wsum[0] + wsum[1] + wsum[2] + wsum[3]);
}

// rep + gate + x0
__global__ void rep_gate(const float* __restrict__ e, const float* __restrict__ denom,
                         const float* __restrict__ keys, const float* __restrict__ queries,
                         const float* __restrict__ Wg, const float* __restrict__ bg,
                         float* __restrict__ x0) {
    __shared__ float att[512];
    __shared__ float urow[256];
    const int tid = threadIdx.x;
    const int row = blockIdx.x;      // b*128 + q
    const int b = row >> 7, q = row & 127;
    const float inv = 1.f / denom[q];
    att[tid] = e[row * 512 + tid] * inv;
    att[tid + 256] = e[row * 512 + 256 + tid] * inv;
    __syncthreads();
    float racc = 0.f;
#pragma unroll 4
    for (int k = 0; k < 512; ++k) racc += att[k] * keys[(b * 512 + k) * 256 + tid];
    const float u = queries[row * 256 + tid] + racc;
    urow[tid] = u;
    __syncthreads();
    const float4* uv = (const float4*)urow;
    const float4* wr = (const float4*)(Wg + tid * 256);
    float g = 0.f;
#pragma unroll 8
    for (int k4 = 0; k4 < 64; ++k4) {
        float4 a = uv[k4];
        float4 wq = wr[k4];
        g += a.x * wq.x + a.y * wq.y + a.z * wq.z + a.w * wq.w;
    }
    g += bg[tid];
    x0[row * 256 + tid] = fast_sigmoid(g) * u;
}

// Sequential GRU layer: round-6 PASSING kernel, byte-identical (305us, absmax
// 1.95e-3). Deferred-store is BANNED: r7/r8/r9 all failed (3.3e-2/3.5e-2/NaN)
// and defer was the only common ingredient (r9 bisect). 1 WG, 4 waves (1/SIMD,
// 512-reg unified budget/wave). Wave w owns cols [64w,64w+64) of all 3 gates =
// 12 tiles: 8 pinned in AGPR via inline-asm MFMA ("a" B-operand), 4 in VGPR via
// builtin. Single barrier/step.
__launch_bounds__(256, 1)
__global__ void gru_seq(const float* __restrict__ gi,    // [4][128][768] (bih + bhh_rz folded)
                        const float* __restrict__ whh,   // [768][256] f32 row-major
                        const float* __restrict__ bhh,   // [768] (n-part used)
                        float* __restrict__ xout) {      // [4][128][256]
    // abuf[buf][grp=ks*4+khi][physrow][j]: bf16 A-frags, physrow = logicalrow ^ (grp&15)
    __shared__ __align__(16) ushort abuf[2][32][16][8];   // 16KB
    __shared__ float gibuf[2][3072];                      // 24KB (gi row dbuf)
    __shared__ float gbuf[3][4][256];                     // 12KB [gate][batch][col]

    const int tid = threadIdx.x;
    const int lane = tid & 63, w = tid >> 6;
    const int l15 = lane & 15, lhi = lane >> 4;

    // zero both abuf buffers (logical rows 4..15 must read as zero -> padded M)
    for (int i = tid; i < 8192; i += 256) ((ushort*)abuf)[i] = 0;

    // B-fragment preload (f32 -> bf16): tile i = g*4+c covers Whh rows
    // g*256 + 64w + 16c + l15, k = ks*32 + lhi*8 + j. Tiles 0-3 -> VGPR (builtin),
    // tiles 4-11 -> AGPR (inline asm, 256 AGPRs exactly).
    short8 bf_v[4][8];
    i32x4  bf_a[8][8];
#pragma unroll
    for (int i = 0; i < 12; ++i) {
        const int g = i >> 2, c = i & 3;
        const float* basef = whh + (g * 256 + w * 64 + c * 16 + l15) * 256 + lhi * 8;
#pragma unroll
        for (int ks = 0; ks < 8; ++ks) {
            const float4 a0 = *(const float4*)(basef + ks * 32);
            const float4 a1 = *(const float4*)(basef + ks * 32 + 4);
            short8 v;
            v[0] = (short)f2bf(a0.x); v[1] = (short)f2bf(a0.y);
            v[2] = (short)f2bf(a0.z); v[3] = (short)f2bf(a0.w);
            v[4] = (short)f2bf(a1.x); v[5] = (short)f2bf(a1.y);
            v[6] = (short)f2bf(a1.z); v[7] = (short)f2bf(a1.w);
            if (i < 4) bf_v[i][ks] = v;
            else       bf_a[i - 4][ks] = __builtin_bit_cast(i32x4, v);
        }
    }

    // phase-B mapping (wave-local): thread = (batch pb_b, cols pb_c..pb_c+3) within wave w's 64 cols
    const int pb_b = lhi;                    // 0..3
    const int pb_c = (w << 6) + (l15 << 2);  // wave-local col block
    const f32x4 bn4 = *(const f32x4*)(bhh + 512 + pb_c);  // n-gate hidden bias
    float hreg[4] = {0.f, 0.f, 0.f, 0.f};

    // preload gi row 0 into gibuf[0]
#pragma unroll
    for (int m = 0; m < 12; ++m) {
        const int j = tid + 256 * m;
        const int b = j / 768, c = j - b * 768;
        gibuf[0][j] = gi[b * 98304 + c];
    }
    __syncthreads();

    for (int t = 0; t < 128; ++t) {
        // async prefetch gi row t+1 -> gibuf[(t+1)&1]; 64-lane chunks never cross a
        // batch boundary (768 % 64 == 0): wave-uniform LDS base + lane*4 contract ok.
        if (t < 127) {
#pragma unroll
            for (int m = 0; m < 12; ++m) {
                const int jw = m * 256 + (w << 6);
                const int jl = jw + lane;
                const int b = jl / 768, c = jl - b * 768;
                const float* gsrc = gi + b * 98304 + (t + 1) * 768 + c;
                __builtin_amdgcn_global_load_lds(
                    (const __attribute__((address_space(1))) unsigned int*)gsrc,
                    (__attribute__((address_space(3))) unsigned int*)&gibuf[(t + 1) & 1][jw],
                    4, 0, 0);
            }
        }
        // phase A: gh = h~ @ Whh^T (reads abuf[t&1], XOR-swizzled rows)
        f32x4 acc[12];
#pragma unroll
        for (int i = 0; i < 12; ++i)
#pragma unroll
            for (int cc = 0; cc < 4; ++cc) acc[i][cc] = 0.f;
#pragma unroll
        for (int ks = 0; ks < 8; ++ks) {
            const int grp = ks * 4 + lhi;
            const short8 a = *(const short8*)&abuf[t & 1][grp][l15 ^ (grp & 15)][0];
#pragma unroll
            for (int i = 0; i < 4; ++i)
                acc[i] = __builtin_amdgcn_mfma_f32_16x16x32_bf16(a, bf_v[i][ks], acc[i], 0, 0, 0);
#pragma unroll
            for (int i = 0; i < 8; ++i)
                asm("v_mfma_f32_16x16x32_bf16 %0, %1, %2, %0"
                    : "+v"(acc[4 + i])
                    : "v"(a), "a"(bf_a[i][ks]));
        }
        // acc -> gbuf: lanes 0-15 hold real rows (b = reg idx), col = l15.
        // Wave-local (wave w writes/reads only its 64 cols) -> no barrier, the
        // compiler orders the w->r via lgkmcnt.
        if (lane < 16) {
#pragma unroll
            for (int g = 0; g < 3; ++g)
#pragma unroll
                for (int c = 0; c < 4; ++c)
#pragma unroll
                    for (int b = 0; b < 4; ++b)
                        gbuf[g][b][(w << 6) + (c << 4) + l15] = acc[g * 4 + c][b];
        }

        // phase B: 64 lanes/wave, 4 cells each (batch pb_b, cols pb_c..pb_c+3)
        {
            const float* gcur = gibuf[t & 1];
            const f32x4 gr = *(const f32x4*)&gbuf[0][pb_b][pb_c];
            const f32x4 gz = *(const f32x4*)&gbuf[1][pb_b][pb_c];
            const f32x4 gn = *(const f32x4*)&gbuf[2][pb_b][pb_c];
            const f32x4 ir = *(const f32x4*)&gcur[pb_b * 768 + pb_c];
            const f32x4 iz = *(const f32x4*)&gcur[pb_b * 768 + 256 + pb_c];
            const f32x4 in_ = *(const f32x4*)&gcur[pb_b * 768 + 512 + pb_c];
            f32x4 xo;
            short4_t hb;
#pragma unroll
            for (int j = 0; j < 4; ++j) {
                const float r = fast_sigmoid(ir[j] + gr[j]);       // biases pre-folded in gi
                const float z = fast_sigmoid(iz[j] + gz[j]);
                const float hn_pre = gn[j] + bn4[j];               // bhh_n not foldable (r*)
                const float nn = fast_tanh(in_[j] + r * hn_pre);
                const float h2 = nn + z * (hreg[j] - nn);
                hreg[j] = h2;
                xo[j] = h2;
                hb[j] = (short)f2bf(h2);
            }
            *(f32x4*)&xout[(pb_b * 128 + t) * 256 + pb_c] = xo;
            // abuf write for step t+1: 4 bf16 at col pb_c (pb_c&7 in {0,4} -> 8B aligned)
            const int grp = pb_c >> 3;
            ushort* dst = &abuf[(t + 1) & 1][grp][pb_b ^ (grp & 15)][pb_c & 7];
            *(short4_t*)dst = hb;
        }
        // single barrier/step: publishes abuf[(t+1)] cross-wave and gibuf[(t+1)]
        // (syncthreads drains vmcnt -> global_load_lds data visible).
        __syncthreads();
    }
}

extern "C" void kernel_launch(void* const* d_in, const int* in_sizes, int n_in,
                              void* d_out, int out_size, void* d_ws, size_t ws_size,
                              hipStream_t stream) {
    (void)in_sizes; (void)n_in; (void)out_size; (void)ws_size;
    const float* keys    = (const float*)d_in[0];
    const float* queries = (const float*)d_in[1];
    const float* W_k     = (const float*)d_in[2];
    const float* W_q     = (const float*)d_in[3];
    const float* w_v     = (const float*)d_in[4];
    const float* W_g_w   = (const float*)d_in[5];
    const float* W_g_b   = (const float*)d_in[6];
    const float* Wih     = (const float*)d_in[7];
    const float* Whh     = (const float*)d_in[8];
    const float* bih     = (const float*)d_in[9];
    const float* bhh     = (const float*)d_in[10];

    float* ws = (float*)d_ws;
    float* Kp_gi = ws;             // 524288 (Kp; reused as gi after attention phase)
    float* Qp   = ws + 524288;     // 131072
    float* e    = ws + 655360;     // 262144
    float* den  = ws + 917504;     // 256 (128 used)
    float* xA   = ws + 917760;     // 131072
    float* xB   = ws + 1048832;    // 131072

    hipMemsetAsync((void*)den, 0, 512, stream);

    gemm_rowwise8<<<256, 256, 0, stream>>>(keys, W_k, nullptr, nullptr, Kp_gi, 256);
    gemm_rowwise8<<<64, 256, 0, stream>>>(queries, W_q, nullptr, nullptr, Qp, 256);
    attn_scores<<<512, 256, 0, stream>>>(Kp_gi, Qp, w_v, e, den);
    rep_gate<<<512, 256, 0, stream>>>(e, den, keys, queries, W_g_w, W_g_b, xA);

    float* gi = Kp_gi;   // Kp dead after attn_scores
    // gi GEMM bias: bih fully, plus bhh folded into r,z halves (n<512)
    gemm_rowwise8<<<64, 256, 0, stream>>>(xA, Wih, bih, bhh, gi, 768);
    gru_seq<<<1, 256, 0, stream>>>(gi, Whh, bhh, xB);
    gemm_rowwise8<<<64, 256, 0, stream>>>(xB, Wih + 196608, bih + 768, bhh + 768, gi, 768);
    gru_seq<<<1, 256, 0, stream>>>(gi, Whh + 196608, bhh + 768, xA);
    gemm_rowwise8<<<64, 256, 0, stream>>>(xA, Wih + 393216, bih + 1536, bhh + 1536, gi, 768);
    gru_seq<<<1, 256, 0, stream>>>(gi, Whh + 393216, bhh + 1536, (float*)d_out);
}

// Round 12
// 881.608 us; speedup vs baseline: 1.7557x; 1.2382x over previous
//
#include <hip/hip_runtime.h>
#include <hip/hip_bf16.h>

// Problem constants: B=4, LK=512, LQ=128, D=256, H=256, L=3
// out: x [4,128,256] float32

typedef __attribute__((ext_vector_type(8))) short short8;
typedef __attribute__((ext_vector_type(4))) short short4_t;
typedef __attribute__((ext_vector_type(4))) float f32x4;
typedef __attribute__((ext_vector_type(4))) int i32x4;
typedef unsigned short ushort;
typedef unsigned int uint;

__device__ __forceinline__ float fast_rcp(float x) { return __builtin_amdgcn_rcpf(x); }
__device__ __forceinline__ float fast_tanh(float x) {
    float e = __expf(2.f * x);
    return 1.f - 2.f * fast_rcp(1.f + e);
}
__device__ __forceinline__ float fast_sigmoid(float x) {
    return fast_rcp(1.f + __expf(-x));
}
__device__ __forceinline__ ushort f2bf(float v) {
    unsigned int b = __builtin_bit_cast(unsigned int, v);
    unsigned int r = (b + 0x7fffu + ((b >> 16) & 1u)) >> 16;
    return (ushort)r;
}

// 8-rows-per-block GEMM. tb=0: out[row*N+n]. tb=1 (gi stream layout): row=(b*128+t)
// is remapped to out[(t*4+b)*768+n].
__global__ void gemm_rowwise8(const float* __restrict__ in, const float* __restrict__ W,
                              const float* __restrict__ bias, const float* __restrict__ bias2,
                              float* __restrict__ out, int N, int tb) {
    __shared__ float xrow[8][256];
    const int tid = threadIdx.x;
    const int row0 = blockIdx.x * 8;
#pragma unroll
    for (int r = 0; r < 8; ++r) xrow[r][tid] = in[(row0 + r) * 256 + tid];
    __syncthreads();
    for (int n = tid; n < N; n += 256) {
        const float4* wv = (const float4*)(W + n * 256);
        float s[8] = {0.f, 0.f, 0.f, 0.f, 0.f, 0.f, 0.f, 0.f};
#pragma unroll 4
        for (int k4 = 0; k4 < 64; ++k4) {
            const float4 b = wv[k4];
#pragma unroll
            for (int r = 0; r < 8; ++r) {
                const float4 a = ((const float4*)xrow[r])[k4];   // broadcast read (free)
                s[r] += a.x * b.x + a.y * b.y + a.z * b.z + a.w * b.w;
            }
        }
        float bb = 0.f;
        if (bias) bb += bias[n];
        if (bias2 && n < 512) bb += bias2[n];
#pragma unroll
        for (int r = 0; r < 8; ++r) {
            const int row = row0 + r;
            if (tb) out[((row & 127) * 4 + (row >> 7)) * 768 + n] = s[r] + bb;
            else    out[row * N + n] = s[r] + bb;
        }
    }
}

// e[b,q,k] = exp( sum_h w_v[h]*tanh(Qp[b,q,h]+Kp[b,k,h]) ); denom[q] += sum over (b,k)
__global__ void attn_scores(const float* __restrict__ Kp, const float* __restrict__ Qp,
                            const float* __restrict__ wv, float* __restrict__ e,
                            float* __restrict__ denom) {
    __shared__ float qrow[256];
    __shared__ float wvr[256];
    __shared__ float wsum[4];
    const int tid = threadIdx.x;
    const int row = blockIdx.x;      // b*128 + q
    const int b = row >> 7, q = row & 127;
    qrow[tid] = Qp[row * 256 + tid];
    wvr[tid] = wv[tid];
    __syncthreads();
    const int lane = tid & 63, w = tid >> 6;
    const float4 qv = ((const float4*)qrow)[lane];
    const float4 wvv = ((const float4*)wvr)[lane];
    float dsum = 0.f;
    for (int k = w; k < 512; k += 4) {
        const float4 kv = *(const float4*)(Kp + (b * 512 + k) * 256 + lane * 4);
        float s = fast_tanh(qv.x + kv.x) * wvv.x;
        s += fast_tanh(qv.y + kv.y) * wvv.y;
        s += fast_tanh(qv.z + kv.z) * wvv.z;
        s += fast_tanh(qv.w + kv.w) * wvv.w;
#pragma unroll
        for (int m = 1; m < 64; m <<= 1) s += __shfl_xor(s, m);
        if (lane == 0) {
            float ev = __expf(s);
            e[row * 512 + k] = ev;
            dsum += ev;
        }
    }
    if (lane == 0) wsum[w] = dsum;
    __syncthreads();
    if (tid == 0) atomicAdd(&denom[q], wsum[0] + wsum[1] + wsum[2] + wsum[3]);
}

// rep + gate + x0
__global__ void rep_gate(const float* __restrict__ e, const float* __restrict__ denom,
                         const float* __restrict__ keys, const float* __restrict__ queries,
                         const float* __restrict__ Wg, const float* __restrict__ bg,
                         float* __restrict__ x0) {
    __shared__ float att[512];
    __shared__ float urow[256];
    const int tid = threadIdx.x;
    const int row = blockIdx.x;      // b*128 + q
    const int b = row >> 7, q = row & 127;
    const float inv = 1.f / denom[q];
    att[tid] = e[row * 512 + tid] * inv;
    att[tid + 256] = e[row * 512 + 256 + tid] * inv;
    __syncthreads();
    float racc = 0.f;
#pragma unroll 4
    for (int k = 0; k < 512; ++k) racc += att[k] * keys[(b * 512 + k) * 256 + tid];
    const float u = queries[row * 256 + tid] + racc;
    urow[tid] = u;
    __syncthreads();
    const float4* uv = (const float4*)urow;
    const float4* wr = (const float4*)(Wg + tid * 256);
    float g = 0.f;
#pragma unroll 8
    for (int k4 = 0; k4 < 64; ++k4) {
        float4 a = uv[k4];
        float4 wq = wr[k4];
        g += a.x * wq.x + a.y * wq.y + a.z * wq.z + a.w * wq.w;
    }
    g += bg[tid];
    x0[row * 256 + tid] = fast_sigmoid(g) * u;
}

// Layer-pipelined GRU: grid=5, one block per role on its own CU.
//   role 0 = W0 (layer-0 recurrence)  -> xbf0 stream + flags[0]
//   role 1 = P1 (gi1 = x0 @ Wih1^T)   -> gi1 stream + flags[1]
//   role 2 = W1                       -> xbf1 stream + flags[2]
//   role 3 = P2 (gi2 = x1 @ Wih2^T)   -> gi2 stream + flags[3]
//   role 4 = W2                       -> d_out (f32)
// W-role = r10's PASSING gru_seq verbatim (4 waves, 8 AGPR-asm + 4 VGPR-builtin
// Whh tiles, XOR abuf, single barrier/step) + additive changes only: [t][b][c]
// gi layout, flag polls, bf16-x stream store, flag publish. Defer-store BANNED
// (r9). 8-wave BANNED (r7/r8/r11). Dependencies are acyclic with full-length
// stream buffers -> deadlock-free under any block scheduling (worst case
// degrades to sequential execution, still correct).
// Cross-XCD handoff: producer __syncthreads (drains stores) -> tid0
// __threadfence (L2 writeback) -> atomicExch; consumer atomicAdd-poll ->
// __threadfence (invalidate: required, consumer L2 may cache prior replay).
__global__ __launch_bounds__(256, 1)
void gru_pipe(const float* __restrict__ gi0,
              float* __restrict__ gi1, float* __restrict__ gi2,
              const float* __restrict__ whh, const float* __restrict__ bhh,
              const float* __restrict__ wih, const float* __restrict__ bih,
              ushort* __restrict__ xbf0, ushort* __restrict__ xbf1,
              uint* __restrict__ flags, float* __restrict__ dout) {
    __shared__ __align__(16) ushort abuf[2][32][16][8];   // 16KB (P uses abuf[0])
    __shared__ float gibuf[2][3072];                      // 24KB (W only)
    __shared__ float gbuf[3][4][256];                     // 12KB (W only)

    const int role = blockIdx.x;
    const int tid = threadIdx.x;
    const int lane = tid & 63, w = tid >> 6;
    const int l15 = lane & 15, lhi = lane >> 4;

    if ((role & 1) == 0) {
        // ---------------- W role: recurrence for layer l ----------------
        const int l = role >> 1;
        const float* gi    = (l == 0) ? gi0 : (l == 1) ? gi1 : gi2;  // [128][4][768]
        const float* whh_l = whh + l * 196608;
        const float* bhh_l = bhh + l * 768;
        uint* gcnt  = (l == 1) ? &flags[1] : (l == 2) ? &flags[3] : nullptr;
        ushort* xbf = (l == 0) ? xbf0 : (l == 1) ? xbf1 : nullptr;   // [128][4][256] bf16
        uint* xcnt  = (l == 0) ? &flags[0] : (l == 1) ? &flags[2] : nullptr;

        for (int i = tid; i < 8192; i += 256) ((ushort*)abuf)[i] = 0;

        short8 bf_v[4][8];
        i32x4  bf_a[8][8];
#pragma unroll
        for (int i = 0; i < 12; ++i) {
            const int g = i >> 2, c = i & 3;
            const float* basef = whh_l + (g * 256 + w * 64 + c * 16 + l15) * 256 + lhi * 8;
#pragma unroll
            for (int ks = 0; ks < 8; ++ks) {
                const float4 a0 = *(const float4*)(basef + ks * 32);
                const float4 a1 = *(const float4*)(basef + ks * 32 + 4);
                short8 v;
                v[0] = (short)f2bf(a0.x); v[1] = (short)f2bf(a0.y);
                v[2] = (short)f2bf(a0.z); v[3] = (short)f2bf(a0.w);
                v[4] = (short)f2bf(a1.x); v[5] = (short)f2bf(a1.y);
                v[6] = (short)f2bf(a1.z); v[7] = (short)f2bf(a1.w);
                if (i < 4) bf_v[i][ks] = v;
                else       bf_a[i - 4][ks] = __builtin_bit_cast(i32x4, v);
            }
        }

        const int pb_b = lhi;
        const int pb_c = (w << 6) + (l15 << 2);
        const f32x4 bn4 = *(const f32x4*)(bhh_l + 512 + pb_c);
        float hreg[4] = {0.f, 0.f, 0.f, 0.f};

        // gi row 0 preload (poll first for l1/l2)
        if (gcnt) {
            while (atomicAdd(gcnt, 0u) < 1u) __builtin_amdgcn_s_sleep(1);
            __threadfence();
        }
#pragma unroll
        for (int m = 0; m < 12; ++m) gibuf[0][tid + 256 * m] = gi[tid + 256 * m];
        __syncthreads();

        for (int t = 0; t < 128; ++t) {
            // async prefetch gi row t+1 (poll producer first)
            if (t < 127) {
                if (gcnt) {
                    while (atomicAdd(gcnt, 0u) < (uint)(t + 2)) __builtin_amdgcn_s_sleep(1);
                    __threadfence();
                }
#pragma unroll
                for (int m = 0; m < 12; ++m) {
                    const int jw = m * 256 + (w << 6);
                    __builtin_amdgcn_global_load_lds(
                        (const __attribute__((address_space(1))) unsigned int*)(gi + (t + 1) * 3072 + jw + lane),
                        (__attribute__((address_space(3))) unsigned int*)&gibuf[(t + 1) & 1][jw],
                        4, 0, 0);
                }
            }
            // phase A: gh = h~ @ Whh^T (reads abuf[t&1], XOR-swizzled rows)
            f32x4 acc[12];
#pragma unroll
            for (int i = 0; i < 12; ++i)
#pragma unroll
                for (int cc = 0; cc < 4; ++cc) acc[i][cc] = 0.f;
#pragma unroll
            for (int ks = 0; ks < 8; ++ks) {
                const int grp = ks * 4 + lhi;
                const short8 a = *(const short8*)&abuf[t & 1][grp][l15 ^ (grp & 15)][0];
#pragma unroll
                for (int i = 0; i < 4; ++i)
                    acc[i] = __builtin_amdgcn_mfma_f32_16x16x32_bf16(a, bf_v[i][ks], acc[i], 0, 0, 0);
#pragma unroll
                for (int i = 0; i < 8; ++i)
                    asm("v_mfma_f32_16x16x32_bf16 %0, %1, %2, %0"
                        : "+v"(acc[4 + i])
                        : "v"(a), "a"(bf_a[i][ks]));
            }
            // acc -> gbuf (wave-local; same-wave LDS ordering, r10-proven)
            if (lane < 16) {
#pragma unroll
                for (int g = 0; g < 3; ++g)
#pragma unroll
                    for (int c = 0; c < 4; ++c)
#pragma unroll
                        for (int b = 0; b < 4; ++b)
                            gbuf[g][b][(w << 6) + (c << 4) + l15] = acc[g * 4 + c][b];
            }
            // phase B
            {
                const float* gcur = gibuf[t & 1];
                const f32x4 gr = *(const f32x4*)&gbuf[0][pb_b][pb_c];
                const f32x4 gz = *(const f32x4*)&gbuf[1][pb_b][pb_c];
                const f32x4 gn = *(const f32x4*)&gbuf[2][pb_b][pb_c];
                const f32x4 ir = *(const f32x4*)&gcur[pb_b * 768 + pb_c];
                const f32x4 iz = *(const f32x4*)&gcur[pb_b * 768 + 256 + pb_c];
                const f32x4 in_ = *(const f32x4*)&gcur[pb_b * 768 + 512 + pb_c];
                f32x4 xo;
                short4_t hb;
#pragma unroll
                for (int j = 0; j < 4; ++j) {
                    const float r = fast_sigmoid(ir[j] + gr[j]);
                    const float z = fast_sigmoid(iz[j] + gz[j]);
                    const float nn = fast_tanh(in_[j] + r * (gn[j] + bn4[j]));
                    const float h2 = nn + z * (hreg[j] - nn);
                    hreg[j] = h2;
                    xo[j] = h2;
                    hb[j] = (short)f2bf(h2);
                }
                if (xbf) *(short4_t*)&xbf[t * 1024 + pb_b * 256 + pb_c] = hb;   // immediate store
                else     *(f32x4*)&dout[(pb_b * 128 + t) * 256 + pb_c] = xo;    // layer 2
                const int grp = pb_c >> 3;
                *(short4_t*)&abuf[(t + 1) & 1][grp][pb_b ^ (grp & 15)][pb_c & 7] = hb;
            }
            __syncthreads();   // abuf[t+1] + gibuf[t+1] published; stores drained
            if (xcnt && tid == 0) { __threadfence(); atomicExch(xcnt, (uint)(t + 1)); }
        }
    } else {
        // ---------------- P role: gi_{pl}[t] = x_{pl-1}[t] @ Wih_pl^T + bias ----------------
        const int pl = (role + 1) >> 1;                 // 1 or 2
        const ushort* xbf = (pl == 1) ? xbf0 : xbf1;
        uint* xcnt  = (pl == 1) ? &flags[0] : &flags[2];
        float* gout = (pl == 1) ? gi1 : gi2;
        uint* gcnt  = (pl == 1) ? &flags[1] : &flags[3];
        const float* wih_l = wih + pl * 196608;
        const float* bih_l = bih + pl * 768;
        const float* bhh_l = bhh + pl * 768;

        for (int i = tid; i < 4096; i += 256) ((ushort*)abuf)[i] = 0;   // abuf[0]

        short8 pf_v[4][8];
        i32x4  pf_a[8][8];
        int   n12[12];
        float b12[12];
#pragma unroll
        for (int i = 0; i < 12; ++i) {
            const int g = i >> 2, c = i & 3;
            const int n = g * 256 + w * 64 + c * 16 + l15;
            n12[i] = n;
            b12[i] = bih_l[n] + (n < 512 ? bhh_l[n] : 0.f);
            const float* basef = wih_l + n * 256 + lhi * 8;
#pragma unroll
            for (int ks = 0; ks < 8; ++ks) {
                const float4 a0 = *(const float4*)(basef + ks * 32);
                const float4 a1 = *(const float4*)(basef + ks * 32 + 4);
                short8 v;
                v[0] = (short)f2bf(a0.x); v[1] = (short)f2bf(a0.y);
                v[2] = (short)f2bf(a0.z); v[3] = (short)f2bf(a0.w);
                v[4] = (short)f2bf(a1.x); v[5] = (short)f2bf(a1.y);
                v[6] = (short)f2bf(a1.z); v[7] = (short)f2bf(a1.w);
                if (i < 4) pf_v[i][ks] = v;
                else       pf_a[i - 4][ks] = __builtin_bit_cast(i32x4, v);
            }
        }
        const int pb_b = lhi;
        const int pb_c = (w << 6) + (l15 << 2);
        __syncthreads();

        for (int t = 0; t < 128; ++t) {
            while (atomicAdd(xcnt, 0u) < (uint)(t + 1)) __builtin_amdgcn_s_sleep(1);
            __threadfence();
            // stage x[t] (bf16) into abuf[0] with the XOR layout
            const short4_t xv = *(const short4_t*)&xbf[t * 1024 + pb_b * 256 + pb_c];
            {
                const int grp = pb_c >> 3;
                *(short4_t*)&abuf[0][grp][pb_b ^ (grp & 15)][pb_c & 7] = xv;
            }
            __syncthreads();
            f32x4 acc[12];
#pragma unroll
            for (int i = 0; i < 12; ++i)
#pragma unroll
                for (int cc = 0; cc < 4; ++cc) acc[i][cc] = 0.f;
#pragma unroll
            for (int ks = 0; ks < 8; ++ks) {
                const int grp = ks * 4 + lhi;
                const short8 a = *(const short8*)&abuf[0][grp][l15 ^ (grp & 15)][0];
#pragma unroll
                for (int i = 0; i < 4; ++i)
                    acc[i] = __builtin_amdgcn_mfma_f32_16x16x32_bf16(a, pf_v[i][ks], acc[i], 0, 0, 0);
#pragma unroll
                for (int i = 0; i < 8; ++i)
                    asm("v_mfma_f32_16x16x32_bf16 %0, %1, %2, %0"
                        : "+v"(acc[4 + i])
                        : "v"(a), "a"(pf_a[i][ks]));
            }
            if (lane < 16) {
#pragma unroll
                for (int i = 0; i < 12; ++i)
#pragma unroll
                    for (int b = 0; b < 4; ++b)
                        gout[t * 3072 + b * 768 + n12[i]] = acc[i][b] + b12[i];
            }
            __syncthreads();   // drains the gout stores (vmcnt(0) before barrier)
            if (tid == 0) { __threadfence(); atomicExch(gcnt, (uint)(t + 1)); }
        }
    }
}

extern "C" void kernel_launch(void* const* d_in, const int* in_sizes, int n_in,
                              void* d_out, int out_size, void* d_ws, size_t ws_size,
                              hipStream_t stream) {
    (void)in_sizes; (void)n_in; (void)out_size; (void)ws_size;
    const float* keys    = (const float*)d_in[0];
    const float* queries = (const float*)d_in[1];
    const float* W_k     = (const float*)d_in[2];
    const float* W_q     = (const float*)d_in[3];
    const float* w_v     = (const float*)d_in[4];
    const float* W_g_w   = (const float*)d_in[5];
    const float* W_g_b   = (const float*)d_in[6];
    const float* Wih     = (const float*)d_in[7];
    const float* Whh     = (const float*)d_in[8];
    const float* bih     = (const float*)d_in[9];
    const float* bhh     = (const float*)d_in[10];

    float* ws = (float*)d_ws;
    float* Kp_gi0 = ws;              // 524288 (Kp; first 393216 reused as gi0)
    float* Qp    = ws + 524288;      // 131072
    float* e     = ws + 655360;      // 262144 (dead after rep_gate; overlaid by gi1)
    float* den   = ws + 917504;      // 256
    float* xA    = ws + 917760;      // 131072 (dead after gi0 gemm)
    float* gi1   = ws + 655360;      // 393216 (overlays e+den+xA, all dead by pipe time)
    float* gi2   = ws + 1048576;     // 393216
    ushort* xbf0 = (ushort*)(ws + 1441792);  // 131072 ushort = 65536 float slots
    ushort* xbf1 = (ushort*)(ws + 1507328);  // 131072 ushort
    uint*  flags = (uint*)(ws + 1572864);    // 4

    hipMemsetAsync((void*)den, 0, 512, stream);
    hipMemsetAsync((void*)flags, 0, 16, stream);

    gemm_rowwise8<<<256, 256, 0, stream>>>(keys, W_k, nullptr, nullptr, Kp_gi0, 256, 0);
    gemm_rowwise8<<<64, 256, 0, stream>>>(queries, W_q, nullptr, nullptr, Qp, 256, 0);
    attn_scores<<<512, 256, 0, stream>>>(Kp_gi0, Qp, w_v, e, den);
    rep_gate<<<512, 256, 0, stream>>>(e, den, keys, queries, W_g_w, W_g_b, xA);

    float* gi0 = Kp_gi0;   // Kp dead after attn_scores
    // gi0 = x0 @ Wih0^T + bih0 + bhh0_rz, in [t][b][c] stream layout
    gemm_rowwise8<<<64, 256, 0, stream>>>(xA, Wih, bih, bhh, gi0, 768, 1);

    gru_pipe<<<5, 256, 0, stream>>>(gi0, gi1, gi2, Whh, bhh, Wih, bih,
                                    xbf0, xbf1, flags, (float*)d_out);
}

// Round 13
// 710.675 us; speedup vs baseline: 2.1780x; 1.2405x over previous
//
#include <hip/hip_runtime.h>
#include <hip/hip_bf16.h>

// Problem constants: B=4, LK=512, LQ=128, D=256, H=256, L=3
// out: x [4,128,256] float32

typedef __attribute__((ext_vector_type(8))) short short8;
typedef __attribute__((ext_vector_type(4))) short short4_t;
typedef __attribute__((ext_vector_type(4))) float f32x4;
typedef __attribute__((ext_vector_type(4))) int i32x4;
typedef unsigned short ushort;
typedef unsigned int uint;

__device__ __forceinline__ float fast_rcp(float x) { return __builtin_amdgcn_rcpf(x); }
__device__ __forceinline__ float fast_tanh(float x) {
    float e = __expf(2.f * x);
    return 1.f - 2.f * fast_rcp(1.f + e);
}
__device__ __forceinline__ float fast_sigmoid(float x) {
    return fast_rcp(1.f + __expf(-x));
}
__device__ __forceinline__ ushort f2bf(float v) {
    unsigned int b = __builtin_bit_cast(unsigned int, v);
    unsigned int r = (b + 0x7fffu + ((b >> 16) & 1u)) >> 16;
    return (ushort)r;
}

// 8-rows-per-block GEMM. tb=0: out[row*N+n]. tb=1 (gi stream layout): row=(b*128+t)
// is remapped to out[(t*4+b)*768+n].
__global__ void gemm_rowwise8(const float* __restrict__ in, const float* __restrict__ W,
                              const float* __restrict__ bias, const float* __restrict__ bias2,
                              float* __restrict__ out, int N, int tb) {
    __shared__ float xrow[8][256];
    const int tid = threadIdx.x;
    const int row0 = blockIdx.x * 8;
#pragma unroll
    for (int r = 0; r < 8; ++r) xrow[r][tid] = in[(row0 + r) * 256 + tid];
    __syncthreads();
    for (int n = tid; n < N; n += 256) {
        const float4* wv = (const float4*)(W + n * 256);
        float s[8] = {0.f, 0.f, 0.f, 0.f, 0.f, 0.f, 0.f, 0.f};
#pragma unroll 4
        for (int k4 = 0; k4 < 64; ++k4) {
            const float4 b = wv[k4];
#pragma unroll
            for (int r = 0; r < 8; ++r) {
                const float4 a = ((const float4*)xrow[r])[k4];   // broadcast read (free)
                s[r] += a.x * b.x + a.y * b.y + a.z * b.z + a.w * b.w;
            }
        }
        float bb = 0.f;
        if (bias) bb += bias[n];
        if (bias2 && n < 512) bb += bias2[n];
#pragma unroll
        for (int r = 0; r < 8; ++r) {
            const int row = row0 + r;
            if (tb) out[((row & 127) * 4 + (row >> 7)) * 768 + n] = s[r] + bb;
            else    out[row * N + n] = s[r] + bb;
        }
    }
}

// e[b,q,k] = exp( sum_h w_v[h]*tanh(Qp[b,q,h]+Kp[b,k,h]) ); denom[q] += sum over (b,k)
__global__ void attn_scores(const float* __restrict__ Kp, const float* __restrict__ Qp,
                            const float* __restrict__ wv, float* __restrict__ e,
                            float* __restrict__ denom) {
    __shared__ float qrow[256];
    __shared__ float wvr[256];
    __shared__ float wsum[4];
    const int tid = threadIdx.x;
    const int row = blockIdx.x;      // b*128 + q
    const int b = row >> 7, q = row & 127;
    qrow[tid] = Qp[row * 256 + tid];
    wvr[tid] = wv[tid];
    __syncthreads();
    const int lane = tid & 63, w = tid >> 6;
    const float4 qv = ((const float4*)qrow)[lane];
    const float4 wvv = ((const float4*)wvr)[lane];
    float dsum = 0.f;
    for (int k = w; k < 512; k += 4) {
        const float4 kv = *(const float4*)(Kp + (b * 512 + k) * 256 + lane * 4);
        float s = fast_tanh(qv.x + kv.x) * wvv.x;
        s += fast_tanh(qv.y + kv.y) * wvv.y;
        s += fast_tanh(qv.z + kv.z) * wvv.z;
        s += fast_tanh(qv.w + kv.w) * wvv.w;
#pragma unroll
        for (int m = 1; m < 64; m <<= 1) s += __shfl_xor(s, m);
        if (lane == 0) {
            float ev = __expf(s);
            e[row * 512 + k] = ev;
            dsum += ev;
        }
    }
    if (lane == 0) wsum[w] = dsum;
    __syncthreads();
    if (tid == 0) atomicAdd(&denom[q], wsum[0] + wsum[1] + wsum[2] + wsum[3]);
}

// rep + gate + x0
__global__ void rep_gate(const float* __restrict__ e, const float* __restrict__ denom,
                         const float* __restrict__ keys, const float* __restrict__ queries,
                         const float* __restrict__ Wg, const float* __restrict__ bg,
                         float* __restrict__ x0) {
    __shared__ float att[512];
    __shared__ float urow[256];
    const int tid = threadIdx.x;
    const int row = blockIdx.x;      // b*128 + q
    const int b = row >> 7, q = row & 127;
    const float inv = 1.f / denom[q];
    att[tid] = e[row * 512 + tid] * inv;
    att[tid + 256] = e[row * 512 + 256 + tid] * inv;
    __syncthreads();
    float racc = 0.f;
#pragma unroll 4
    for (int k = 0; k < 512; ++k) racc += att[k] * keys[(b * 512 + k) * 256 + tid];
    const float u = queries[row * 256 + tid] + racc;
    urow[tid] = u;
    __syncthreads();
    const float4* uv = (const float4*)urow;
    const float4* wr = (const float4*)(Wg + tid * 256);
    float g = 0.f;
#pragma unroll 8
    for (int k4 = 0; k4 < 64; ++k4) {
        float4 a = uv[k4];
        float4 wq = wr[k4];
        g += a.x * wq.x + a.y * wq.y + a.z * wq.z + a.w * wq.w;
    }
    g += bg[tid];
    x0[row * 256 + tid] = fast_sigmoid(g) * u;
}

// Layer-pipelined GRU (r12 structure, passed) with GRANULE=4 sync amortization:
// producers publish once per 4 steps (fence cost /4 — r12 evidence: per-step
// threadfence ~3.5us/beat overhead, FETCH 5.95MB of flag/fence traffic);
// consumers poll+acquire once per granule. P-roles batch 4 steps -> M=16 MFMA
// (full M dim, 4x less P work). Roles: 0=W0 2=W1 4=W2 (recurrence), 1=P1 3=P2
// (input projection). Defer-store BANNED (r9); 8-wave BANNED (r7/r8/r11).
// Acyclic deps + full-length buffers -> deadlock-free under any scheduling.
__global__ __launch_bounds__(256, 1)
void gru_pipe(const float* __restrict__ gi0,
              float* __restrict__ gi1, float* __restrict__ gi2,
              const float* __restrict__ whh, const float* __restrict__ bhh,
              const float* __restrict__ wih, const float* __restrict__ bih,
              ushort* __restrict__ xbf0, ushort* __restrict__ xbf1,
              uint* __restrict__ flags, float* __restrict__ dout) {
    __shared__ __align__(16) ushort abuf[2][32][16][8];   // 16KB (P uses abuf[0])
    __shared__ float gibuf[2][3072];                      // 24KB (W only)
    __shared__ float gbuf[3][4][256];                     // 12KB (W only)

    const int role = blockIdx.x;
    const int tid = threadIdx.x;
    const int lane = tid & 63, w = tid >> 6;
    const int l15 = lane & 15, lhi = lane >> 4;

    if ((role & 1) == 0) {
        // ---------------- W role: recurrence for layer l ----------------
        const int l = role >> 1;
        const float* gi    = (l == 0) ? gi0 : (l == 1) ? gi1 : gi2;  // [128][4][768]
        const float* whh_l = whh + l * 196608;
        const float* bhh_l = bhh + l * 768;
        uint* gcnt  = (l == 1) ? &flags[1] : (l == 2) ? &flags[3] : nullptr;
        ushort* xbf = (l == 0) ? xbf0 : (l == 1) ? xbf1 : nullptr;   // [128][4][256] bf16
        uint* xcnt  = (l == 0) ? &flags[0] : (l == 1) ? &flags[2] : nullptr;

        for (int i = tid; i < 8192; i += 256) ((ushort*)abuf)[i] = 0;

        short8 bf_v[4][8];
        i32x4  bf_a[8][8];
#pragma unroll
        for (int i = 0; i < 12; ++i) {
            const int g = i >> 2, c = i & 3;
            const float* basef = whh_l + (g * 256 + w * 64 + c * 16 + l15) * 256 + lhi * 8;
#pragma unroll
            for (int ks = 0; ks < 8; ++ks) {
                const float4 a0 = *(const float4*)(basef + ks * 32);
                const float4 a1 = *(const float4*)(basef + ks * 32 + 4);
                short8 v;
                v[0] = (short)f2bf(a0.x); v[1] = (short)f2bf(a0.y);
                v[2] = (short)f2bf(a0.z); v[3] = (short)f2bf(a0.w);
                v[4] = (short)f2bf(a1.x); v[5] = (short)f2bf(a1.y);
                v[6] = (short)f2bf(a1.z); v[7] = (short)f2bf(a1.w);
                if (i < 4) bf_v[i][ks] = v;
                else       bf_a[i - 4][ks] = __builtin_bit_cast(i32x4, v);
            }
        }

        const int pb_b = lhi;
        const int pb_c = (w << 6) + (l15 << 2);
        const f32x4 bn4 = *(const f32x4*)(bhh_l + 512 + pb_c);
        float hreg[4] = {0.f, 0.f, 0.f, 0.f};

        // gi row 0 preload (granule 0 poll for l1/l2)
        if (gcnt) {
            while (atomicAdd(gcnt, 0u) < 1u) __builtin_amdgcn_s_sleep(1);
            __threadfence();
        }
#pragma unroll
        for (int m = 0; m < 12; ++m) gibuf[0][tid + 256 * m] = gi[tid + 256 * m];
        __syncthreads();

        for (int t = 0; t < 128; ++t) {
            // async prefetch gi row t+1; poll producer only at granule boundary
            if (t < 127) {
                if (gcnt && ((t + 1) & 3) == 0) {
                    const uint need = (uint)(((t + 1) >> 2) + 1);
                    while (atomicAdd(gcnt, 0u) < need) __builtin_amdgcn_s_sleep(1);
                    __threadfence();
                }
#pragma unroll
                for (int m = 0; m < 12; ++m) {
                    const int jw = m * 256 + (w << 6);
                    __builtin_amdgcn_global_load_lds(
                        (const __attribute__((address_space(1))) unsigned int*)(gi + (t + 1) * 3072 + jw + lane),
                        (__attribute__((address_space(3))) unsigned int*)&gibuf[(t + 1) & 1][jw],
                        4, 0, 0);
                }
            }
            // phase A: gh = h~ @ Whh^T (reads abuf[t&1], XOR-swizzled rows)
            f32x4 acc[12];
#pragma unroll
            for (int i = 0; i < 12; ++i)
#pragma unroll
                for (int cc = 0; cc < 4; ++cc) acc[i][cc] = 0.f;
#pragma unroll
            for (int ks = 0; ks < 8; ++ks) {
                const int grp = ks * 4 + lhi;
                const short8 a = *(const short8*)&abuf[t & 1][grp][l15 ^ (grp & 15)][0];
#pragma unroll
                for (int i = 0; i < 4; ++i)
                    acc[i] = __builtin_amdgcn_mfma_f32_16x16x32_bf16(a, bf_v[i][ks], acc[i], 0, 0, 0);
#pragma unroll
                for (int i = 0; i < 8; ++i)
                    asm("v_mfma_f32_16x16x32_bf16 %0, %1, %2, %0"
                        : "+v"(acc[4 + i])
                        : "v"(a), "a"(bf_a[i][ks]));
            }
            // acc -> gbuf (wave-local; same-wave LDS ordering, r10-proven)
            if (lane < 16) {
#pragma unroll
                for (int g = 0; g < 3; ++g)
#pragma unroll
                    for (int c = 0; c < 4; ++c)
#pragma unroll
                        for (int b = 0; b < 4; ++b)
                            gbuf[g][b][(w << 6) + (c << 4) + l15] = acc[g * 4 + c][b];
            }
            // phase B
            {
                const float* gcur = gibuf[t & 1];
                const f32x4 gr = *(const f32x4*)&gbuf[0][pb_b][pb_c];
                const f32x4 gz = *(const f32x4*)&gbuf[1][pb_b][pb_c];
                const f32x4 gn = *(const f32x4*)&gbuf[2][pb_b][pb_c];
                const f32x4 ir = *(const f32x4*)&gcur[pb_b * 768 + pb_c];
                const f32x4 iz = *(const f32x4*)&gcur[pb_b * 768 + 256 + pb_c];
                const f32x4 in_ = *(const f32x4*)&gcur[pb_b * 768 + 512 + pb_c];
                f32x4 xo;
                short4_t hb;
#pragma unroll
                for (int j = 0; j < 4; ++j) {
                    const float r = fast_sigmoid(ir[j] + gr[j]);
                    const float z = fast_sigmoid(iz[j] + gz[j]);
                    const float nn = fast_tanh(in_[j] + r * (gn[j] + bn4[j]));
                    const float h2 = nn + z * (hreg[j] - nn);
                    hreg[j] = h2;
                    xo[j] = h2;
                    hb[j] = (short)f2bf(h2);
                }
                if (xbf) *(short4_t*)&xbf[t * 1024 + pb_b * 256 + pb_c] = hb;   // immediate store
                else     *(f32x4*)&dout[(pb_b * 128 + t) * 256 + pb_c] = xo;    // layer 2
                const int grp = pb_c >> 3;
                *(short4_t*)&abuf[(t + 1) & 1][grp][pb_b ^ (grp & 15)][pb_c & 7] = hb;
            }
            __syncthreads();   // abuf[t+1]+gibuf[t+1] published; all x stores drained
            // publish once per 4-step granule (fence cost amortized 4x vs r12)
            if (xcnt && (t & 3) == 3 && tid == 0) {
                __threadfence();
                atomicExch(xcnt, (uint)((t >> 2) + 1));
            }
        }
    } else {
        // ------- P role: gi_{pl}[4j..4j+3] = x_{pl-1}[granule j] @ Wih_pl^T + bias -------
        // M=16 (4 steps x 4 batches): logical A-row m = s*4 + b.
        const int pl = (role + 1) >> 1;                 // 1 or 2
        const ushort* xbf = (pl == 1) ? xbf0 : xbf1;
        uint* xcnt  = (pl == 1) ? &flags[0] : &flags[2];
        float* gout = (pl == 1) ? gi1 : gi2;
        uint* gcnt  = (pl == 1) ? &flags[1] : &flags[3];
        const float* wih_l = wih + pl * 196608;
        const float* bih_l = bih + pl * 768;
        const float* bhh_l = bhh + pl * 768;

        short8 pf_v[4][8];
        i32x4  pf_a[8][8];
        int   n12[12];
        float b12[12];
#pragma unroll
        for (int i = 0; i < 12; ++i) {
            const int g = i >> 2, c = i & 3;
            const int n = g * 256 + w * 64 + c * 16 + l15;
            n12[i] = n;
            b12[i] = bih_l[n] + (n < 512 ? bhh_l[n] : 0.f);
            const float* basef = wih_l + n * 256 + lhi * 8;
#pragma unroll
            for (int ks = 0; ks < 8; ++ks) {
                const float4 a0 = *(const float4*)(basef + ks * 32);
                const float4 a1 = *(const float4*)(basef + ks * 32 + 4);
                short8 v;
                v[0] = (short)f2bf(a0.x); v[1] = (short)f2bf(a0.y);
                v[2] = (short)f2bf(a0.z); v[3] = (short)f2bf(a0.w);
                v[4] = (short)f2bf(a1.x); v[5] = (short)f2bf(a1.y);
                v[6] = (short)f2bf(a1.z); v[7] = (short)f2bf(a1.w);
                if (i < 4) pf_v[i][ks] = v;
                else       pf_a[i - 4][ks] = __builtin_bit_cast(i32x4, v);
            }
        }
        const int pb_c = (w << 6) + (l15 << 2);
        __syncthreads();

        for (int j = 0; j < 32; ++j) {
            while (atomicAdd(xcnt, 0u) < (uint)(j + 1)) __builtin_amdgcn_s_sleep(1);
            __threadfence();
            // stage granule: thread (lhi=b, pb_c) stages rows m = s*4+lhi, s=0..3
#pragma unroll
            for (int s = 0; s < 4; ++s) {
                const short4_t xv = *(const short4_t*)&xbf[(4 * j + s) * 1024 + lhi * 256 + pb_c];
                const int m = s * 4 + lhi;
                const int grp = pb_c >> 3;
                *(short4_t*)&abuf[0][grp][m ^ (grp & 15)][pb_c & 7] = xv;
            }
            __syncthreads();
            f32x4 acc[12];
#pragma unroll
            for (int i = 0; i < 12; ++i)
#pragma unroll
                for (int cc = 0; cc < 4; ++cc) acc[i][cc] = 0.f;
#pragma unroll
            for (int ks = 0; ks < 8; ++ks) {
                const int grp = ks * 4 + lhi;
                const short8 a = *(const short8*)&abuf[0][grp][l15 ^ (grp & 15)][0];
#pragma unroll
                for (int i = 0; i < 4; ++i)
                    acc[i] = __builtin_amdgcn_mfma_f32_16x16x32_bf16(a, pf_v[i][ks], acc[i], 0, 0, 0);
#pragma unroll
                for (int i = 0; i < 8; ++i)
                    asm("v_mfma_f32_16x16x32_bf16 %0, %1, %2, %0"
                        : "+v"(acc[4 + i])
                        : "v"(a), "a"(pf_a[i][ks]));
            }
            // output: lane (lhi,l15) reg r holds row m=lhi*4+r -> t=4j+lhi, batch=r
#pragma unroll
            for (int i = 0; i < 12; ++i)
#pragma unroll
                for (int b = 0; b < 4; ++b)
                    gout[(4 * j + lhi) * 3072 + b * 768 + n12[i]] = acc[i][b] + b12[i];
            __syncthreads();   // drains gout stores + all abuf reads done
            if (tid == 0) { __threadfence(); atomicExch(gcnt, (uint)(j + 1)); }
        }
    }
}

extern "C" void kernel_launch(void* const* d_in, const int* in_sizes, int n_in,
                              void* d_out, int out_size, void* d_ws, size_t ws_size,
                              hipStream_t stream) {
    (void)in_sizes; (void)n_in; (void)out_size; (void)ws_size;
    const float* keys    = (const float*)d_in[0];
    const float* queries = (const float*)d_in[1];
    const float* W_k     = (const float*)d_in[2];
    const float* W_q     = (const float*)d_in[3];
    const float* w_v     = (const float*)d_in[4];
    const float* W_g_w   = (const float*)d_in[5];
    const float* W_g_b   = (const float*)d_in[6];
    const float* Wih     = (const float*)d_in[7];
    const float* Whh     = (const float*)d_in[8];
    const float* bih     = (const float*)d_in[9];
    const float* bhh     = (const float*)d_in[10];

    float* ws = (float*)d_ws;
    float* Kp_gi0 = ws;              // 524288 (Kp; first 393216 reused as gi0)
    float* Qp    = ws + 524288;      // 131072
    float* e     = ws + 655360;      // 262144 (dead after rep_gate; overlaid by gi1)
    float* den   = ws + 917504;      // 256
    float* xA    = ws + 917760;      // 131072 (dead after gi0 gemm)
    float* gi1   = ws + 655360;      // 393216 (overlays e+den+xA, all dead by pipe time)
    float* gi2   = ws + 1048576;     // 393216
    ushort* xbf0 = (ushort*)(ws + 1441792);  // 131072 ushort
    ushort* xbf1 = (ushort*)(ws + 1507328);  // 131072 ushort
    uint*  flags = (uint*)(ws + 1572864);    // 4

    hipMemsetAsync((void*)den, 0, 512, stream);
    hipMemsetAsync((void*)flags, 0, 16, stream);

    gemm_rowwise8<<<256, 256, 0, stream>>>(keys, W_k, nullptr, nullptr, Kp_gi0, 256, 0);
    gemm_rowwise8<<<64, 256, 0, stream>>>(queries, W_q, nullptr, nullptr, Qp, 256, 0);
    attn_scores<<<512, 256, 0, stream>>>(Kp_gi0, Qp, w_v, e, den);
    rep_gate<<<512, 256, 0, stream>>>(e, den, keys, queries, W_g_w, W_g_b, xA);

    float* gi0 = Kp_gi0;   // Kp dead after attn_scores
    // gi0 = x0 @ Wih0^T + bih0 + bhh0_rz, in [t][b][c] stream layout
    gemm_rowwise8<<<64, 256, 0, stream>>>(xA, Wih, bih, bhh, gi0, 768, 1);

    gru_pipe<<<5, 256, 0, stream>>>(gi0, gi1, gi2, Whh, bhh, Wih, bih,
                                    xbf0, xbf1, flags, (float*)d_out);
}

// Round 14
// 708.504 us; speedup vs baseline: 2.1847x; 1.0031x over previous
//
#include <hip/hip_runtime.h>
#include <hip/hip_bf16.h>

// Problem constants: B=4, LK=512, LQ=128, D=256, H=256, L=3
// out: x [4,128,256] float32

typedef __attribute__((ext_vector_type(8))) short short8;
typedef __attribute__((ext_vector_type(4))) short short4_t;
typedef __attribute__((ext_vector_type(4))) float f32x4;
typedef __attribute__((ext_vector_type(4))) int i32x4;
typedef unsigned short ushort;
typedef unsigned int uint;

__device__ __forceinline__ float fast_rcp(float x) { return __builtin_amdgcn_rcpf(x); }
__device__ __forceinline__ float fast_tanh(float x) {
    float e = __expf(2.f * x);
    return 1.f - 2.f * fast_rcp(1.f + e);
}
__device__ __forceinline__ float fast_sigmoid(float x) {
    return fast_rcp(1.f + __expf(-x));
}
__device__ __forceinline__ ushort f2bf(float v) {
    unsigned int b = __builtin_bit_cast(unsigned int, v);
    unsigned int r = (b + 0x7fffu + ((b >> 16) & 1u)) >> 16;
    return (ushort)r;
}

// 8-rows-per-block GEMM. tb=0: out[row*N+n]. tb=1 (gi stream layout): row=(b*128+t)
// is remapped to out[(t*4+b)*768+n].
__global__ void gemm_rowwise8(const float* __restrict__ in, const float* __restrict__ W,
                              const float* __restrict__ bias, const float* __restrict__ bias2,
                              float* __restrict__ out, int N, int tb) {
    __shared__ float xrow[8][256];
    const int tid = threadIdx.x;
    const int row0 = blockIdx.x * 8;
#pragma unroll
    for (int r = 0; r < 8; ++r) xrow[r][tid] = in[(row0 + r) * 256 + tid];
    __syncthreads();
    for (int n = tid; n < N; n += 256) {
        const float4* wv = (const float4*)(W + n * 256);
        float s[8] = {0.f, 0.f, 0.f, 0.f, 0.f, 0.f, 0.f, 0.f};
#pragma unroll 4
        for (int k4 = 0; k4 < 64; ++k4) {
            const float4 b = wv[k4];
#pragma unroll
            for (int r = 0; r < 8; ++r) {
                const float4 a = ((const float4*)xrow[r])[k4];   // broadcast read (free)
                s[r] += a.x * b.x + a.y * b.y + a.z * b.z + a.w * b.w;
            }
        }
        float bb = 0.f;
        if (bias) bb += bias[n];
        if (bias2 && n < 512) bb += bias2[n];
#pragma unroll
        for (int r = 0; r < 8; ++r) {
            const int row = row0 + r;
            if (tb) out[((row & 127) * 4 + (row >> 7)) * 768 + n] = s[r] + bb;
            else    out[row * N + n] = s[r] + bb;
        }
    }
}

// e[b,q,k] = exp( sum_h w_v[h]*tanh(Qp[b,q,h]+Kp[b,k,h]) ); denom[q] += sum over (b,k)
__global__ void attn_scores(const float* __restrict__ Kp, const float* __restrict__ Qp,
                            const float* __restrict__ wv, float* __restrict__ e,
                            float* __restrict__ denom) {
    __shared__ float qrow[256];
    __shared__ float wvr[256];
    __shared__ float wsum[4];
    const int tid = threadIdx.x;
    const int row = blockIdx.x;      // b*128 + q
    const int b = row >> 7, q = row & 127;
    qrow[tid] = Qp[row * 256 + tid];
    wvr[tid] = wv[tid];
    __syncthreads();
    const int lane = tid & 63, w = tid >> 6;
    const float4 qv = ((const float4*)qrow)[lane];
    const float4 wvv = ((const float4*)wvr)[lane];
    float dsum = 0.f;
    for (int k = w; k < 512; k += 4) {
        const float4 kv = *(const float4*)(Kp + (b * 512 + k) * 256 + lane * 4);
        float s = fast_tanh(qv.x + kv.x) * wvv.x;
        s += fast_tanh(qv.y + kv.y) * wvv.y;
        s += fast_tanh(qv.z + kv.z) * wvv.z;
        s += fast_tanh(qv.w + kv.w) * wvv.w;
#pragma unroll
        for (int m = 1; m < 64; m <<= 1) s += __shfl_xor(s, m);
        if (lane == 0) {
            float ev = __expf(s);
            e[row * 512 + k] = ev;
            dsum += ev;
        }
    }
    if (lane == 0) wsum[w] = dsum;
    __syncthreads();
    if (tid == 0) atomicAdd(&denom[q], wsum[0] + wsum[1] + wsum[2] + wsum[3]);
}

// rep + gate + x0
__global__ void rep_gate(const float* __restrict__ e, const float* __restrict__ denom,
                         const float* __restrict__ keys, const float* __restrict__ queries,
                         const float* __restrict__ Wg, const float* __restrict__ bg,
                         float* __restrict__ x0) {
    __shared__ float att[512];
    __shared__ float urow[256];
    const int tid = threadIdx.x;
    const int row = blockIdx.x;      // b*128 + q
    const int b = row >> 7, q = row & 127;
    const float inv = 1.f / denom[q];
    att[tid] = e[row * 512 + tid] * inv;
    att[tid + 256] = e[row * 512 + 256 + tid] * inv;
    __syncthreads();
    float racc = 0.f;
#pragma unroll 4
    for (int k = 0; k < 512; ++k) racc += att[k] * keys[(b * 512 + k) * 256 + tid];
    const float u = queries[row * 256 + tid] + racc;
    urow[tid] = u;
    __syncthreads();
    const float4* uv = (const float4*)urow;
    const float4* wr = (const float4*)(Wg + tid * 256);
    float g = 0.f;
#pragma unroll 8
    for (int k4 = 0; k4 < 64; ++k4) {
        float4 a = uv[k4];
        float4 wq = wr[k4];
        g += a.x * wq.x + a.y * wq.y + a.z * wq.z + a.w * wq.w;
    }
    g += bg[tid];
    x0[row * 256 + tid] = fast_sigmoid(g) * u;
}

// Single-thread poll: tid0 spins on the flag, everyone else parks at the
// barrier; then ALL threads acquire-fence. r13 evidence: 256-thread polls on
// 4 same-cacheline flags = serialized atomics ~2us/beat.
__device__ __forceinline__ void poll_flag(const uint* cnt, uint need, int tid) {
    if (tid == 0) {
        while (atomicAdd((uint*)cnt, 0u) < need) __builtin_amdgcn_s_sleep(1);
    }
    __syncthreads();
    __threadfence();   // acquire: invalidate stale L1/L2 lines before data reads
}

// Layer-pipelined GRU (r13 structure, passed): GRANULE=4 publish/poll, P-roles
// M=16. This round: flags padded 128B apart + single-thread poll (the two
// de-contention fixes). Roles: 0=W0 2=W1 4=W2, 1=P1 3=P2.
// Defer-store BANNED (r9); 8-wave BANNED (r7/r8/r11). Acyclic deps +
// full-length buffers -> deadlock-free.
__global__ __launch_bounds__(256, 1)
void gru_pipe(const float* __restrict__ gi0,
              float* __restrict__ gi1, float* __restrict__ gi2,
              const float* __restrict__ whh, const float* __restrict__ bhh,
              const float* __restrict__ wih, const float* __restrict__ bih,
              ushort* __restrict__ xbf0, ushort* __restrict__ xbf1,
              uint* __restrict__ flags, float* __restrict__ dout) {
    __shared__ __align__(16) ushort abuf[2][32][16][8];   // 16KB (P uses abuf[0])
    __shared__ float gibuf[2][3072];                      // 24KB (W only)
    __shared__ float gbuf[3][4][256];                     // 12KB (W only)

    const int role = blockIdx.x;
    const int tid = threadIdx.x;
    const int lane = tid & 63, w = tid >> 6;
    const int l15 = lane & 15, lhi = lane >> 4;

    // flags padded: counter i at flags[i*32] (128B apart, distinct cachelines)
    uint* f_x0 = flags + 0;    // W0 -> P1
    uint* f_g1 = flags + 32;   // P1 -> W1
    uint* f_x1 = flags + 64;   // W1 -> P2
    uint* f_g2 = flags + 96;   // P2 -> W2

    if ((role & 1) == 0) {
        // ---------------- W role: recurrence for layer l ----------------
        const int l = role >> 1;
        const float* gi    = (l == 0) ? gi0 : (l == 1) ? gi1 : gi2;  // [128][4][768]
        const float* whh_l = whh + l * 196608;
        const float* bhh_l = bhh + l * 768;
        uint* gcnt  = (l == 1) ? f_g1 : (l == 2) ? f_g2 : nullptr;
        ushort* xbf = (l == 0) ? xbf0 : (l == 1) ? xbf1 : nullptr;   // [128][4][256] bf16
        uint* xcnt  = (l == 0) ? f_x0 : (l == 1) ? f_x1 : nullptr;

        for (int i = tid; i < 8192; i += 256) ((ushort*)abuf)[i] = 0;

        short8 bf_v[4][8];
        i32x4  bf_a[8][8];
#pragma unroll
        for (int i = 0; i < 12; ++i) {
            const int g = i >> 2, c = i & 3;
            const float* basef = whh_l + (g * 256 + w * 64 + c * 16 + l15) * 256 + lhi * 8;
#pragma unroll
            for (int ks = 0; ks < 8; ++ks) {
                const float4 a0 = *(const float4*)(basef + ks * 32);
                const float4 a1 = *(const float4*)(basef + ks * 32 + 4);
                short8 v;
                v[0] = (short)f2bf(a0.x); v[1] = (short)f2bf(a0.y);
                v[2] = (short)f2bf(a0.z); v[3] = (short)f2bf(a0.w);
                v[4] = (short)f2bf(a1.x); v[5] = (short)f2bf(a1.y);
                v[6] = (short)f2bf(a1.z); v[7] = (short)f2bf(a1.w);
                if (i < 4) bf_v[i][ks] = v;
                else       bf_a[i - 4][ks] = __builtin_bit_cast(i32x4, v);
            }
        }

        const int pb_b = lhi;
        const int pb_c = (w << 6) + (l15 << 2);
        const f32x4 bn4 = *(const f32x4*)(bhh_l + 512 + pb_c);
        float hreg[4] = {0.f, 0.f, 0.f, 0.f};

        // gi row 0 preload (granule 0 poll for l1/l2)
        if (gcnt) poll_flag(gcnt, 1u, tid);
#pragma unroll
        for (int m = 0; m < 12; ++m) gibuf[0][tid + 256 * m] = gi[tid + 256 * m];
        __syncthreads();

        for (int t = 0; t < 128; ++t) {
            // async prefetch gi row t+1; poll producer only at granule boundary
            if (t < 127) {
                if (gcnt && ((t + 1) & 3) == 0)
                    poll_flag(gcnt, (uint)(((t + 1) >> 2) + 1), tid);
#pragma unroll
                for (int m = 0; m < 12; ++m) {
                    const int jw = m * 256 + (w << 6);
                    __builtin_amdgcn_global_load_lds(
                        (const __attribute__((address_space(1))) unsigned int*)(gi + (t + 1) * 3072 + jw + lane),
                        (__attribute__((address_space(3))) unsigned int*)&gibuf[(t + 1) & 1][jw],
                        4, 0, 0);
                }
            }
            // phase A: gh = h~ @ Whh^T (reads abuf[t&1], XOR-swizzled rows)
            f32x4 acc[12];
#pragma unroll
            for (int i = 0; i < 12; ++i)
#pragma unroll
                for (int cc = 0; cc < 4; ++cc) acc[i][cc] = 0.f;
#pragma unroll
            for (int ks = 0; ks < 8; ++ks) {
                const int grp = ks * 4 + lhi;
                const short8 a = *(const short8*)&abuf[t & 1][grp][l15 ^ (grp & 15)][0];
#pragma unroll
                for (int i = 0; i < 4; ++i)
                    acc[i] = __builtin_amdgcn_mfma_f32_16x16x32_bf16(a, bf_v[i][ks], acc[i], 0, 0, 0);
#pragma unroll
                for (int i = 0; i < 8; ++i)
                    asm("v_mfma_f32_16x16x32_bf16 %0, %1, %2, %0"
                        : "+v"(acc[4 + i])
                        : "v"(a), "a"(bf_a[i][ks]));
            }
            // acc -> gbuf (wave-local; same-wave LDS ordering, r10-proven)
            if (lane < 16) {
#pragma unroll
                for (int g = 0; g < 3; ++g)
#pragma unroll
                    for (int c = 0; c < 4; ++c)
#pragma unroll
                        for (int b = 0; b < 4; ++b)
                            gbuf[g][b][(w << 6) + (c << 4) + l15] = acc[g * 4 + c][b];
            }
            // phase B
            {
                const float* gcur = gibuf[t & 1];
                const f32x4 gr = *(const f32x4*)&gbuf[0][pb_b][pb_c];
                const f32x4 gz = *(const f32x4*)&gbuf[1][pb_b][pb_c];
                const f32x4 gn = *(const f32x4*)&gbuf[2][pb_b][pb_c];
                const f32x4 ir = *(const f32x4*)&gcur[pb_b * 768 + pb_c];
                const f32x4 iz = *(const f32x4*)&gcur[pb_b * 768 + 256 + pb_c];
                const f32x4 in_ = *(const f32x4*)&gcur[pb_b * 768 + 512 + pb_c];
                f32x4 xo;
                short4_t hb;
#pragma unroll
                for (int j = 0; j < 4; ++j) {
                    const float r = fast_sigmoid(ir[j] + gr[j]);
                    const float z = fast_sigmoid(iz[j] + gz[j]);
                    const float nn = fast_tanh(in_[j] + r * (gn[j] + bn4[j]));
                    const float h2 = nn + z * (hreg[j] - nn);
                    hreg[j] = h2;
                    xo[j] = h2;
                    hb[j] = (short)f2bf(h2);
                }
                if (xbf) *(short4_t*)&xbf[t * 1024 + pb_b * 256 + pb_c] = hb;   // immediate store
                else     *(f32x4*)&dout[(pb_b * 128 + t) * 256 + pb_c] = xo;    // layer 2
                const int grp = pb_c >> 3;
                *(short4_t*)&abuf[(t + 1) & 1][grp][pb_b ^ (grp & 15)][pb_c & 7] = hb;
            }
            __syncthreads();   // abuf[t+1]+gibuf[t+1] published; all x stores drained
            // publish once per 4-step granule
            if (xcnt && (t & 3) == 3 && tid == 0) {
                __threadfence();
                atomicExch(xcnt, (uint)((t >> 2) + 1));
            }
        }
    } else {
        // ------- P role: gi_{pl}[4j..4j+3] = x_{pl-1}[granule j] @ Wih_pl^T + bias -------
        // M=16 (4 steps x 4 batches): logical A-row m = s*4 + b.
        const int pl = (role + 1) >> 1;                 // 1 or 2
        const ushort* xbf = (pl == 1) ? xbf0 : xbf1;
        uint* xcnt  = (pl == 1) ? f_x0 : f_x1;
        float* gout = (pl == 1) ? gi1 : gi2;
        uint* gcnt  = (pl == 1) ? f_g1 : f_g2;
        const float* wih_l = wih + pl * 196608;
        const float* bih_l = bih + pl * 768;
        const float* bhh_l = bhh + pl * 768;

        short8 pf_v[4][8];
        i32x4  pf_a[8][8];
        int   n12[12];
        float b12[12];
#pragma unroll
        for (int i = 0; i < 12; ++i) {
            const int g = i >> 2, c = i & 3;
            const int n = g * 256 + w * 64 + c * 16 + l15;
            n12[i] = n;
            b12[i] = bih_l[n] + (n < 512 ? bhh_l[n] : 0.f);
            const float* basef = wih_l + n * 256 + lhi * 8;
#pragma unroll
            for (int ks = 0; ks < 8; ++ks) {
                const float4 a0 = *(const float4*)(basef + ks * 32);
                const float4 a1 = *(const float4*)(basef + ks * 32 + 4);
                short8 v;
                v[0] = (short)f2bf(a0.x); v[1] = (short)f2bf(a0.y);
                v[2] = (short)f2bf(a0.z); v[3] = (short)f2bf(a0.w);
                v[4] = (short)f2bf(a1.x); v[5] = (short)f2bf(a1.y);
                v[6] = (short)f2bf(a1.z); v[7] = (short)f2bf(a1.w);
                if (i < 4) pf_v[i][ks] = v;
                else       pf_a[i - 4][ks] = __builtin_bit_cast(i32x4, v);
            }
        }
        const int pb_c = (w << 6) + (l15 << 2);
        __syncthreads();

        for (int j = 0; j < 32; ++j) {
            poll_flag(xcnt, (uint)(j + 1), tid);
            // stage granule: thread (lhi=b, pb_c) stages rows m = s*4+lhi, s=0..3
#pragma unroll
            for (int s = 0; s < 4; ++s) {
                const short4_t xv = *(const short4_t*)&xbf[(4 * j + s) * 1024 + lhi * 256 + pb_c];
                const int m = s * 4 + lhi;
                const int grp = pb_c >> 3;
                *(short4_t*)&abuf[0][grp][m ^ (grp & 15)][pb_c & 7] = xv;
            }
            __syncthreads();
            f32x4 acc[12];
#pragma unroll
            for (int i = 0; i < 12; ++i)
#pragma unroll
                for (int cc = 0; cc < 4; ++cc) acc[i][cc] = 0.f;
#pragma unroll
            for (int ks = 0; ks < 8; ++ks) {
                const int grp = ks * 4 + lhi;
                const short8 a = *(const short8*)&abuf[0][grp][l15 ^ (grp & 15)][0];
#pragma unroll
                for (int i = 0; i < 4; ++i)
                    acc[i] = __builtin_amdgcn_mfma_f32_16x16x32_bf16(a, pf_v[i][ks], acc[i], 0, 0, 0);
#pragma unroll
                for (int i = 0; i < 8; ++i)
                    asm("v_mfma_f32_16x16x32_bf16 %0, %1, %2, %0"
                        : "+v"(acc[4 + i])
                        : "v"(a), "a"(pf_a[i][ks]));
            }
            // output: lane (lhi,l15) reg r holds row m=lhi*4+r -> t=4j+lhi, batch=r
#pragma unroll
            for (int i = 0; i < 12; ++i)
#pragma unroll
                for (int b = 0; b < 4; ++b)
                    gout[(4 * j + lhi) * 3072 + b * 768 + n12[i]] = acc[i][b] + b12[i];
            __syncthreads();   // drains gout stores + all abuf reads done
            if (tid == 0) { __threadfence(); atomicExch(gcnt, (uint)(j + 1)); }
        }
    }
}

extern "C" void kernel_launch(void* const* d_in, const int* in_sizes, int n_in,
                              void* d_out, int out_size, void* d_ws, size_t ws_size,
                              hipStream_t stream) {
    (void)in_sizes; (void)n_in; (void)out_size; (void)ws_size;
    const float* keys    = (const float*)d_in[0];
    const float* queries = (const float*)d_in[1];
    const float* W_k     = (const float*)d_in[2];
    const float* W_q     = (const float*)d_in[3];
    const float* w_v     = (const float*)d_in[4];
    const float* W_g_w   = (const float*)d_in[5];
    const float* W_g_b   = (const float*)d_in[6];
    const float* Wih     = (const float*)d_in[7];
    const float* Whh     = (const float*)d_in[8];
    const float* bih     = (const float*)d_in[9];
    const float* bhh     = (const float*)d_in[10];

    float* ws = (float*)d_ws;
    float* Kp_gi0 = ws;              // 524288 (Kp; first 393216 reused as gi0)
    float* Qp    = ws + 524288;      // 131072
    float* e     = ws + 655360;      // 262144 (dead after rep_gate; overlaid by gi1)
    float* den   = ws + 917504;      // 256
    float* xA    = ws + 917760;      // 131072 (dead after gi0 gemm)
    float* gi1   = ws + 655360;      // 393216 (overlays e+den+xA, all dead by pipe time)
    float* gi2   = ws + 1048576;     // 393216
    ushort* xbf0 = (ushort*)(ws + 1441792);  // 131072 ushort
    ushort* xbf1 = (ushort*)(ws + 1507328);  // 131072 ushort
    uint*  flags = (uint*)(ws + 1572864);    // 4 counters, 128B apart (512B total)

    hipMemsetAsync((void*)den, 0, 512, stream);
    hipMemsetAsync((void*)flags, 0, 512, stream);

    gemm_rowwise8<<<256, 256, 0, stream>>>(keys, W_k, nullptr, nullptr, Kp_gi0, 256, 0);
    gemm_rowwise8<<<64, 256, 0, stream>>>(queries, W_q, nullptr, nullptr, Qp, 256, 0);
    attn_scores<<<512, 256, 0, stream>>>(Kp_gi0, Qp, w_v, e, den);
    rep_gate<<<512, 256, 0, stream>>>(e, den, keys, queries, W_g_w, W_g_b, xA);

    float* gi0 = Kp_gi0;   // Kp dead after attn_scores
    // gi0 = x0 @ Wih0^T + bih0 + bhh0_rz, in [t][b][c] stream layout
    gemm_rowwise8<<<64, 256, 0, stream>>>(xA, Wih, bih, bhh, gi0, 768, 1);

    gru_pipe<<<5, 256, 0, stream>>>(gi0, gi1, gi2, Whh, bhh, Wih, bih,
                                    xbf0, xbf1, flags, (float*)d_out);
}